// Round 11
// baseline (274.336 us; speedup 1.0000x reference)
//
#include <hip/hip_runtime.h>
#include <cstddef>

#define P_ 4096   // H*W
#define HW_ 64

typedef __bf16 bf16x8 __attribute__((ext_vector_type(8)));
typedef float f32x4 __attribute__((ext_vector_type(4)));

__device__ inline ushort f2bf(float f) {
  unsigned u = __float_as_uint(f);
  unsigned r = (u + 0x7FFFu + ((u >> 16) & 1u)) >> 16;
  return (ushort)r;
}
__device__ inline float bf2f(ushort h) {
  return __uint_as_float(((unsigned)h) << 16);
}
__device__ inline unsigned pack2(ushort a, ushort b) {
  return (unsigned)a | ((unsigned)b << 16);
}

// ---------------- device helpers ----------------

// transpose+split one 128k x 64p tile: src [K][P] fp32 -> dst [P][K] bf16 hi/lo
__device__ inline void xsplit_body(const float* sb, ushort* dhb, ushort* dlb,
                                   int p0, int K, char* smem) {
  float (*T)[65] = (float(*)[65])smem;
  int t = threadIdx.x;
#pragma unroll
  for (int i = 0; i < 32; ++i) {
    int l = i * 256 + t;
    int n = l >> 6, c = l & 63;
    T[n][c] = sb[(size_t)n * P_ + p0 + c];
  }
  __syncthreads();
#pragma unroll
  for (int i = 0; i < 4; ++i) {
    int l = i * 256 + t;
    int c = l >> 4, n8 = (l & 15) << 3;
    ushort vh[8], vl[8];
#pragma unroll
    for (int u = 0; u < 8; ++u) {
      float f = T[n8 + u][c];
      ushort h = f2bf(f);
      vh[u] = h;
      vl[u] = f2bf(f - bf2f(h));
    }
    *(uint4*)&dhb[(size_t)(p0 + c) * K + n8] = *(uint4*)vh;
    *(uint4*)&dlb[(size_t)(p0 + c) * K + n8] = *(uint4*)vl;
  }
}

// split-bf16 GEMM 64x64 tile body (R7 proven version — NO register prefetch;
// R8's 64-VGPR prefetch spilled to scratch: WRITE_SIZE 29->110MB regression)
__device__ inline void gemm_body(const ushort* Whb, const ushort* Wlb,
                                 const ushort* Xhb, const ushort* Xlb,
                                 const float* bias, float* out, int M, int m0,
                                 int p0, int b, int K, char* smem) {
  ushort* Wsh = (ushort*)smem;
  ushort* Wsl = (ushort*)(smem + 9216);
  ushort* Xsh = (ushort*)(smem + 18432);
  ushort* Xsl = (ushort*)(smem + 27648);
  int t = threadIdx.x;
  int w = t >> 6, lane = t & 63, lm = lane & 15, lq = lane >> 4;
  f32x4 C[4];
#pragma unroll
  for (int pt = 0; pt < 4; ++pt) C[pt] = (f32x4)(0.f);
  for (int k0 = 0; k0 < K; k0 += 64) {
#pragma unroll
    for (int i = 0; i < 2; ++i) {
      int u = i * 256 + t;
      int row = u >> 3, k8 = (u & 7) * 8;
      *(uint4*)&Wsh[row * 72 + k8] = *(const uint4*)&Whb[(size_t)row * K + k0 + k8];
      *(uint4*)&Wsl[row * 72 + k8] = *(const uint4*)&Wlb[(size_t)row * K + k0 + k8];
      *(uint4*)&Xsh[row * 72 + k8] = *(const uint4*)&Xhb[(size_t)row * K + k0 + k8];
      *(uint4*)&Xsl[row * 72 + k8] = *(const uint4*)&Xlb[(size_t)row * K + k0 + k8];
    }
    __syncthreads();
#pragma unroll
    for (int kt = 0; kt < 2; ++kt) {
      bf16x8 Ah = *(const bf16x8*)&Wsh[(w * 16 + lm) * 72 + kt * 32 + lq * 8];
      bf16x8 Al = *(const bf16x8*)&Wsl[(w * 16 + lm) * 72 + kt * 32 + lq * 8];
#pragma unroll
      for (int pt = 0; pt < 4; ++pt) {
        bf16x8 Bh = *(const bf16x8*)&Xsh[(pt * 16 + lm) * 72 + kt * 32 + lq * 8];
        bf16x8 Bl = *(const bf16x8*)&Xsl[(pt * 16 + lm) * 72 + kt * 32 + lq * 8];
        C[pt] = __builtin_amdgcn_mfma_f32_16x16x32_bf16(Ah, Bh, C[pt], 0, 0, 0);
        C[pt] = __builtin_amdgcn_mfma_f32_16x16x32_bf16(Al, Bh, C[pt], 0, 0, 0);
        C[pt] = __builtin_amdgcn_mfma_f32_16x16x32_bf16(Ah, Bl, C[pt], 0, 0, 0);
      }
    }
    __syncthreads();
  }
#pragma unroll
  for (int pt = 0; pt < 4; ++pt) {
    int p = p0 + pt * 16 + lm;
#pragma unroll
    for (int r = 0; r < 4; ++r) {
      int m = m0 + w * 16 + lq * 4 + r;
      float v = C[pt][r];
      if (bias) v += bias[m];
      out[((size_t)b * M + m) * P_ + p] = v;
    }
  }
}

// ---------------- K1: lka chain + prep + mean + xsplit(x) ----------------
// grid 1524: [0,512) lka chain; [512,608) wT; [608,752) weight splits;
//            [752,756) b_cb^T; [756,1268) mean; [1268,1524) xsplit of x
__global__ __launch_bounds__(256) void prep_kernel(
    const float* __restrict__ w_cb, const float* __restrict__ dw1_w,
    const float* __restrict__ lka1_w, const float* __restrict__ c1a_w,
    const float* __restrict__ proj_w, const float* __restrict__ c211_w,
    const float* __restrict__ b_cb, ushort* __restrict__ wT,
    ushort* __restrict__ W5h, ushort* __restrict__ W5l,
    ushort* __restrict__ bth, ushort* __restrict__ btl,
    const float* __restrict__ x, float* __restrict__ mean,
    ushort* __restrict__ XTxh, ushort* __restrict__ XTxl,
    const float* __restrict__ w0, const float* __restrict__ w1,
    float* __restrict__ outlka) {
  __shared__ __align__(16) char smem[48448];
  float (*T)[65] = (float(*)[65])smem;
  int blk = blockIdx.x;
  int t = threadIdx.x;
  if (blk < 512) {
    // lka chain: 5x5 p2 -> 7x7 d3 p9, 4x4 register-blocked float4 LDS reads.
    float* p0a = (float*)smem;             // 68 x 72
    float* p1a = (float*)(smem + 19584);   // 82 x 88
    int bc = blk;
    const float* ib = x + (size_t)bc * P_;
    const float* wp0 = w0 + (size_t)(bc & 255) * 25;
    const float* wp1 = w1 + (size_t)(bc & 255) * 49;
    for (int i = t; i < 4896; i += 256) p0a[i] = 0.f;
    for (int i = t; i < 7216; i += 256) p1a[i] = 0.f;
    __syncthreads();
#pragma unroll
    for (int i = 0; i < 4; ++i) {
      int l = i * 1024 + t * 4;
      int y = l >> 6, xx = l & 63;
      *(float4*)&p0a[(y + 2) * 72 + 4 + xx] = *(const float4*)(ib + l);
    }
    __syncthreads();
    int x0 = (t & 15) * 4, y0 = (t >> 4) * 4;
    {
      float acc[4][4] = {};
#pragma unroll
      for (int ry = 0; ry < 8; ++ry) {
        const float* row = &p0a[(y0 + ry) * 72 + x0];
        float4 v0 = *(const float4*)row;
        float4 v1 = *(const float4*)(row + 4);
        float4 v2 = *(const float4*)(row + 8);
        float rv[12] = {v0.x, v0.y, v0.z, v0.w, v1.x, v1.y, v1.z, v1.w,
                        v2.x, v2.y, v2.z, v2.w};
#pragma unroll
        for (int oy = 0; oy < 4; ++oy) {
          int dy = ry - oy;
          if (dy >= 0 && dy <= 4) {
#pragma unroll
            for (int dx = 0; dx < 5; ++dx) {
              float wv = wp0[dy * 5 + dx];
#pragma unroll
              for (int ox = 0; ox < 4; ++ox)
                acc[oy][ox] += wv * rv[2 + ox + dx];
            }
          }
        }
      }
#pragma unroll
      for (int oy = 0; oy < 4; ++oy) {
        float4 v = {acc[oy][0], acc[oy][1], acc[oy][2], acc[oy][3]};
        *(float4*)&p1a[(y0 + oy + 9) * 88 + 12 + x0] = v;
      }
    }
    __syncthreads();
    {
      float acc[4][4] = {};
#pragma unroll
      for (int ry = 0; ry < 22; ++ry) {
        const float* row = &p1a[(y0 + ry) * 88 + x0];
        float rv[28];
#pragma unroll
        for (int q = 0; q < 7; ++q)
          *(float4*)&rv[q * 4] = *(const float4*)(row + q * 4);
#pragma unroll
        for (int oy = 0; oy < 4; ++oy) {
          int d = ry - oy;
          if (d >= 0 && d <= 18 && (d % 3) == 0) {
            int dy = d / 3;
#pragma unroll
            for (int dx = 0; dx < 7; ++dx) {
              float wv = wp1[dy * 7 + dx];
#pragma unroll
              for (int ox = 0; ox < 4; ++ox)
                acc[oy][ox] += wv * rv[3 + ox + 3 * dx];
            }
          }
        }
      }
      float* ob = outlka + (size_t)bc * P_;
#pragma unroll
      for (int oy = 0; oy < 4; ++oy) {
        float4 v = {acc[oy][0], acc[oy][1], acc[oy][2], acc[oy][3]};
        *(float4*)&ob[(y0 + oy) * 64 + x0] = v;
      }
    }
  } else if (blk < 608) {
    int c0 = (blk - 512) * 64;
#pragma unroll
    for (int i = 0; i < 32; ++i) {
      int l = i * 256 + t;
      int n = l >> 6, c = l & 63;
      T[n][c] = w_cb[(size_t)n * 6144 + c0 + c];
    }
    __syncthreads();
#pragma unroll
    for (int i = 0; i < 4; ++i) {
      int l = i * 256 + t;
      int c = l >> 4, n8 = (l & 15) << 3;
      ushort v[8];
#pragma unroll
      for (int u = 0; u < 8; ++u) v[u] = f2bf(T[n8 + u][c]);
      *(uint4*)&wT[(size_t)(c0 + c) * 128 + n8] = *(uint4*)v;
    }
  } else if (blk < 752) {
    int f = (blk - 608) * 2048 + t * 8;
    const float* srcs[5] = {dw1_w, lka1_w, c1a_w, proj_w, c211_w};
    const int base[6] = {0, 65536, 131072, 196608, 262144, 294912};
    int r = 0;
    while (f >= base[r + 1]) ++r;
    const float* s = srcs[r] + (f - base[r]);
    float4 a = *(const float4*)s;
    float4 b4 = *(const float4*)(s + 4);
    float vv[8] = {a.x, a.y, a.z, a.w, b4.x, b4.y, b4.z, b4.w};
    ushort vh[8], vl[8];
#pragma unroll
    for (int u = 0; u < 8; ++u) {
      ushort h = f2bf(vv[u]);
      vh[u] = h;
      vl[u] = f2bf(vv[u] - bf2f(h));
    }
    *(uint4*)&W5h[f] = *(uint4*)vh;
    *(uint4*)&W5l[f] = *(uint4*)vl;
  } else if (blk < 756) {
    int c0 = (blk - 752) * 64;
#pragma unroll
    for (int i = 0; i < 32; ++i) {
      int l = i * 256 + t;
      int n = l >> 6, c = l & 63;
      T[n][c] = b_cb[(size_t)n * 256 + c0 + c];
    }
    __syncthreads();
#pragma unroll
    for (int i = 0; i < 4; ++i) {
      int l = i * 256 + t;
      int c = l >> 4, n8 = (l & 15) << 3;
      ushort vh[8], vl[8];
#pragma unroll
      for (int u = 0; u < 8; ++u) {
        float fv = T[n8 + u][c];
        ushort h = f2bf(fv);
        vh[u] = h;
        vl[u] = f2bf(fv - bf2f(h));
      }
      *(uint4*)&bth[(size_t)(c0 + c) * 128 + n8] = *(uint4*)vh;
      *(uint4*)&btl[(size_t)(c0 + c) * 128 + n8] = *(uint4*)vl;
    }
  } else if (blk < 1268) {
    int bc = blk - 756;
    const float* xp = x + (size_t)bc * P_;
    float s = 0.f;
    for (int i = t; i < P_; i += 256) s += xp[i];
    float* red = (float*)smem;
    red[t] = s;
    __syncthreads();
    for (int off2 = 128; off2 > 0; off2 >>= 1) {
      if (t < off2) red[t] += red[t + off2];
      __syncthreads();
    }
    if (t == 0) mean[bc] = red[0] * (1.f / P_);
  } else {
    const int K = 256;
    int l = blk - 1268;
    int p0 = (l & 63) * 64;
    int kb = (l >> 6) & 1;
    int b = l >> 7;
    xsplit_body(x + ((size_t)b * K + kb * 128) * P_,
                XTxh + (size_t)b * P_ * K + (size_t)kb * 128,
                XTxl + (size_t)b * P_ * K + (size_t)kb * 128, p0, K, smem);
  }
}

// ---------------- K2: dw1/c1a/c211 GEMMs + c2a gate + xsplit(B6) + sca --------
// grid 2050: [0,1280) gemm tiles; [1280,1792) gate; [1792,2048) xsplit(B6);
//            [2048,2050) sca
__global__ __launch_bounds__(256) void main1_kernel(
    const ushort* __restrict__ Xh, const ushort* __restrict__ Xl,
    const ushort* __restrict__ W5h, const ushort* __restrict__ W5l,
    const float* __restrict__ c211_b, float* __restrict__ dw1_out,
    float* __restrict__ B3, float* __restrict__ att0,
    const float* __restrict__ x, const float* __restrict__ c2aw,
    const float* __restrict__ c2ab, float* __restrict__ sgate,
    const float* __restrict__ B6, ushort* __restrict__ XT2h,
    ushort* __restrict__ XT2l, const float* __restrict__ mean,
    const float* __restrict__ sca_w, const float* __restrict__ sca_b,
    float* __restrict__ sca) {
  __shared__ __align__(16) char smem[36864];
  int blk = blockIdx.x;
  int t = threadIdx.x;
  if (blk < 1280) {
    const int K = 256;
    int p = blk & 63;
    int my = (blk >> 6) % 10;
    int b = blk / 640;
    const ushort *Wh, *Wl;
    float* out;
    const float* bias = nullptr;
    int M, m0;
    if (my < 4) {
      Wh = W5h; Wl = W5l; out = dw1_out; M = 256; m0 = my * 64;
    } else if (my < 8) {
      Wh = W5h + 131072; Wl = W5l + 131072; out = B3; M = 256; m0 = (my - 4) * 64;
    } else {
      Wh = W5h + 262144; Wl = W5l + 262144; out = att0; M = 128;
      m0 = (my - 8) * 64; bias = c211_b;
    }
    int p0 = p * 64;
    gemm_body(Wh + (size_t)m0 * K, Wl + (size_t)m0 * K,
              Xh + ((size_t)b * P_ + p0) * K, Xl + ((size_t)b * P_ + p0) * K,
              bias, out, M, m0, p0, b, K, smem);
  } else if (blk < 1792) {
    int idx = (blk - 1280) * 256 + t;
    int xq = idx & 63, y = (idx >> 6) & 63, go = (idx >> 12) & 15, b = idx >> 16;
    float acc[2];
#pragma unroll
    for (int h = 0; h < 2; ++h) {
      int gc = go + h * 16;
      const float* wr = c2aw + gc * 72;
      const float* xb = x + ((size_t)b * 256 + gc * 8) * P_;
      float ss = c2ab[gc];
      for (int ci = 0; ci < 8; ++ci)
        for (int dy = 0; dy < 3; ++dy) {
          int yy = y + dy - 1;
          if (yy < 0 || yy >= 64) continue;
          for (int dx = 0; dx < 3; ++dx) {
            int xx = xq + dx - 1;
            if (xx < 0 || xx >= 64) continue;
            ss += wr[ci * 9 + dy * 3 + dx] * xb[(size_t)ci * P_ + yy * 64 + xx];
          }
        }
      acc[h] = ss;
    }
    sgate[idx] = acc[0] * acc[1];
  } else if (blk < 2048) {
    const int K = 256;
    int l = blk - 1792;
    int p0 = (l & 63) * 64;
    int kb = (l >> 6) & 1;
    int b = l >> 7;
    xsplit_body(B6 + ((size_t)b * K + kb * 128) * P_,
                XT2h + (size_t)b * P_ * K + (size_t)kb * 128,
                XT2l + (size_t)b * P_ * K + (size_t)kb * 128, p0, K, smem);
  } else {
    int b = blk - 2048, c = t;
    const float* mb = mean + b * 256;
    const float* wr = sca_w + c * 256;
    float s = sca_b[c];
    for (int k = 0; k < 256; ++k) s += wr[k] * mb[k];
    sca[b * 256 + c] = s;
  }
}

// ---------------- K3: lka1 GEMM + c2b_t + dw2/c1b 3x3 planes ----------------
// grid 1792: [0,512) lka1 gemm -> B1; [512,768) c2b_t; [768,1792) dw planes
__global__ __launch_bounds__(256) void k3_kernel(
    const ushort* __restrict__ Wh, const ushort* __restrict__ Wl,
    const ushort* __restrict__ XT2h, const ushort* __restrict__ XT2l,
    const float* __restrict__ lka1_b, float* __restrict__ B1,
    const float* __restrict__ sb, const float* __restrict__ c2bw,
    const float* __restrict__ c2bb, const float* __restrict__ gamma,
    const float* __restrict__ res, ushort* __restrict__ outh,
    ushort* __restrict__ outl, const float* __restrict__ in1,
    const float* __restrict__ w1, float* __restrict__ out1,
    const float* __restrict__ in2, const float* __restrict__ w2,
    float* __restrict__ out2) {
  __shared__ __align__(16) char smem[36864];
  int blk = blockIdx.x;
  int t = threadIdx.x;
  if (blk < 512) {
    const int K = 256;
    int p0 = (blk & 63) * 64;
    int m0 = ((blk >> 6) & 3) * 64;
    int b = blk >> 8;
    gemm_body(Wh + (size_t)m0 * K, Wl + (size_t)m0 * K,
              XT2h + ((size_t)b * P_ + p0) * K, XT2l + ((size_t)b * P_ + p0) * K,
              lka1_b, B1, 256, m0, p0, b, K, smem);
  } else if (blk < 768) {
    const int K = 16, M = 128;
    int l = blk - 512;
    int p0 = (l & 63) * 64;
    int m0 = ((l >> 6) & 1) * 64;
    int b = l >> 7;
    float (*Ws)[68] = (float(*)[68])smem;
    float (*Xs)[68] = (float(*)[68])(smem + 4352 * 4);
    int tm = t >> 4, tp = t & 15;
    float acc[4][4] = {};
    const float* inb = sb + (size_t)b * K * P_;
    {
      int kk = t >> 4, pq = (t & 15) << 2;
      float4 v = *(const float4*)(inb + (size_t)kk * P_ + p0 + pq);
      *(float4*)&Xs[kk][pq] = v;
    }
    {
      int mm = t >> 2, kq = (t & 3) << 2;
      float4 v = *(const float4*)(c2bw + (size_t)(m0 + mm) * K + kq);
      Ws[kq + 0][mm] = v.x; Ws[kq + 1][mm] = v.y;
      Ws[kq + 2][mm] = v.z; Ws[kq + 3][mm] = v.w;
    }
    __syncthreads();
#pragma unroll
    for (int kk = 0; kk < 16; ++kk) {
      const float4 wv = *(const float4*)&Ws[kk][tm << 2];
      const float4 xv = *(const float4*)&Xs[kk][tp << 2];
      const float wa[4] = {wv.x, wv.y, wv.z, wv.w};
      const float xa[4] = {xv.x, xv.y, xv.z, xv.w};
#pragma unroll
      for (int i = 0; i < 4; ++i)
#pragma unroll
        for (int j = 0; j < 4; ++j) acc[i][j] += wa[i] * xa[j];
    }
    float val[4][4];
#pragma unroll
    for (int i = 0; i < 4; ++i) {
      int m = m0 + (tm << 2) + i;
      float bv = c2bb[m], gm = gamma[m];
      float4 rv = *(const float4*)(res + ((size_t)b * M + m) * P_ + p0 + (tp << 2));
      val[i][0] = (acc[i][0] + bv) * gm + rv.x;
      val[i][1] = (acc[i][1] + bv) * gm + rv.y;
      val[i][2] = (acc[i][2] + bv) * gm + rv.z;
      val[i][3] = (acc[i][3] + bv) * gm + rv.w;
    }
#pragma unroll
    for (int j = 0; j < 4; ++j) {
      int p = p0 + (tp << 2) + j;
      ushort vh[4], vl[4];
#pragma unroll
      for (int i = 0; i < 4; ++i) {
        float f = val[i][j];
        ushort h = f2bf(f);
        vh[i] = h;
        vl[i] = f2bf(f - bf2f(h));
      }
      size_t a = ((size_t)b * P_ + p) * 128 + m0 + (tm << 2);
      uint2 hv, lv;
      hv.x = pack2(vh[0], vh[1]); hv.y = pack2(vh[2], vh[3]);
      lv.x = pack2(vl[0], vl[1]); lv.y = pack2(vl[2], vl[3]);
      *(uint2*)&outh[a] = hv;
      *(uint2*)&outl[a] = lv;
    }
  } else {
    // 3x3 depthwise plane: 66 rows x 72 cols, interior at [(y+1)*72 + 4 + x]
    float* pl = (float*)smem;
    int l = blk - 768;
    int which = l >> 9;
    int bc = l & 511;
    const float* in = which ? in2 : in1;
    const float* w = which ? w2 : w1;
    float* out = which ? out2 : out1;
    const float* ib = in + (size_t)bc * P_;
    const float* wp = w + (size_t)(bc & 255) * 9;
    for (int i = t; i < 4752; i += 256) pl[i] = 0.f;
    __syncthreads();
#pragma unroll
    for (int i = 0; i < 4; ++i) {
      int ll = i * 1024 + t * 4;
      int y = ll >> 6, xx = ll & 63;
      *(float4*)&pl[(y + 1) * 72 + 4 + xx] = *(const float4*)(ib + ll);
    }
    __syncthreads();
    int x0 = (t & 15) * 4, y0 = (t >> 4) * 4;
    float acc[4][4] = {};
#pragma unroll
    for (int ry = 0; ry < 6; ++ry) {
      const float* row = &pl[(y0 + ry) * 72 + x0];
      float4 v0 = *(const float4*)row;
      float4 v1 = *(const float4*)(row + 4);
      float4 v2 = *(const float4*)(row + 8);
      float rv[12] = {v0.x, v0.y, v0.z, v0.w, v1.x, v1.y, v1.z, v1.w,
                      v2.x, v2.y, v2.z, v2.w};
#pragma unroll
      for (int oy = 0; oy < 4; ++oy) {
        int dy = ry - oy;
        if (dy >= 0 && dy <= 2) {
#pragma unroll
          for (int dx = 0; dx < 3; ++dx) {
            float wv = wp[dy * 3 + dx];
#pragma unroll
            for (int ox = 0; ox < 4; ++ox)
              acc[oy][ox] += wv * rv[3 + ox + dx];
          }
        }
      }
    }
    float* ob = out + (size_t)bc * P_;
#pragma unroll
    for (int oy = 0; oy < 4; ++oy) {
      float4 v = {acc[oy][0], acc[oy][1], acc[oy][2], acc[oy][3]};
      *(float4*)&ob[(y0 + oy) * 64 + x0] = v;
    }
  }
}

// ---------------- IKBA v3: barrier-free, wave-private LDS ----------------
// grid (64 rows, 16 quads, B), block 256 = 4 independent waves.
// Wave gg handles group gi = quad*4+gg alone: MFMA frags direct from global,
// C->pixel transpose through a wave-private [64][17] LDS tile (in-wave DS
// ordering, NO __syncthreads), pixel-major so apply reads are 4x b128.
// H pass: bias tile computed redundantly per wave (32 MFMAs, ~free at 5%
// MfmaUtil) into the same private buffer -> zero cross-wave dependencies.
__global__ __launch_bounds__(256) void ikba_mfma_kernel(
    const float* __restrict__ in, const ushort* __restrict__ attT,
    const ushort* __restrict__ Wt, int dirH, int wofs,
    const ushort* __restrict__ bth, const ushort* __restrict__ btl,
    const float* __restrict__ uf_ep, const float* __restrict__ ga1,
    const float* __restrict__ x1, const float* __restrict__ lka,
    const float* __restrict__ sca, ushort* __restrict__ pXh,
    ushort* __restrict__ pXl, float* __restrict__ outV) {
  __shared__ float Ts[4][64][17];  // 17408 B, wave-private slice [gg]

  int t = threadIdx.x;
  int b = blockIdx.z;
  int quad = blockIdx.y;
  int y = blockIdx.x;
  int p0 = y * 64;
  int gg = t >> 6;
  int lane = t & 63;
  int lm = lane & 15, lq = lane >> 4;
  int gi = quad * 4 + gg;
  int x = lane;
  float (*Tsw)[17] = Ts[gg];

  // A fragments straight from global (L2-resident)
  const ushort* Wbase = Wt + ((size_t)wofs + (size_t)gi * 48) * 128;
  bf16x8 Af[3][4];
#pragma unroll
  for (int ct = 0; ct < 3; ++ct)
#pragma unroll
    for (int K = 0; K < 4; ++K)
      Af[ct][K] = *(const bf16x8*)&Wbase[(ct * 16 + lm) * 128 + K * 32 + lq * 8];

  const ushort* Ab = attT + ((size_t)b * P_ + p0) * 128;
  f32x4 Cf[3][4];
#pragma unroll
  for (int ct = 0; ct < 3; ++ct)
#pragma unroll
    for (int pt = 0; pt < 4; ++pt) Cf[ct][pt] = (f32x4)(0.f);

#pragma unroll
  for (int pt = 0; pt < 4; ++pt) {
    bf16x8 Bf[4];
#pragma unroll
    for (int K = 0; K < 4; ++K)
      Bf[K] = *(const bf16x8*)&Ab[(pt * 16 + lm) * 128 + K * 32 + lq * 8];
#pragma unroll
    for (int ct = 0; ct < 3; ++ct)
#pragma unroll
      for (int K = 0; K < 4; ++K)
        Cf[ct][pt] = __builtin_amdgcn_mfma_f32_16x16x32_bf16(
            Af[ct][K], Bf[K], Cf[ct][pt], 0, 0, 0);
  }

  // u taps: direct per-thread coalesced global loads
  float u[12];
  const float* inb = in + ((size_t)b * 256 + gi * 4) * P_;
  if (dirH) {
#pragma unroll
    for (int j = 0; j < 12; ++j) {
      int ci = j / 3, tap = j % 3;
      int xx = x + tap - 1;
      u[j] = (xx >= 0 && xx < 64) ? inb[(size_t)ci * P_ + p0 + xx] : 0.f;
    }
  } else {
#pragma unroll
    for (int j = 0; j < 12; ++j) {
      int ci = j / 3, tap = j % 3;
      int yy = y + tap - 1;
      u[j] = (yy >= 0 && yy < 64) ? inb[(size_t)ci * P_ + yy * 64 + x] : 0.f;
    }
  }

  // transpose C tiles through wave-private LDS (pixel-major), NO barriers
  float s4[4] = {0.f, 0.f, 0.f, 0.f};
#pragma unroll
  for (int ct = 0; ct < 3; ++ct) {
#pragma unroll
    for (int pt = 0; pt < 4; ++pt)
#pragma unroll
      for (int r = 0; r < 4; ++r)
        Tsw[pt * 16 + lm][lq * 4 + r] = Cf[ct][pt][r];
    float tv[16];
#pragma unroll
    for (int c4 = 0; c4 < 4; ++c4)
      *(float4*)&tv[c4 * 4] = *(const float4*)&Tsw[x][c4 * 4];
#pragma unroll
    for (int c = 0; c < 16; ++c) {
      int col = ct * 16 + c;
      int i = col / 12, j = col % 12;
      s4[i] += tv[c] * u[j];
    }
  }

  // epilogue
  if (dirH) {
    // bias tile (16ch x 64p) per wave via MFMA; reuse Tsw (in-wave ordered)
    bf16x8 Abh[4], Abl[4];
#pragma unroll
    for (int K = 0; K < 4; ++K) {
      Abh[K] = *(const bf16x8*)&bth[(size_t)(quad * 16 + lm) * 128 + K * 32 + lq * 8];
      Abl[K] = *(const bf16x8*)&btl[(size_t)(quad * 16 + lm) * 128 + K * 32 + lq * 8];
    }
#pragma unroll
    for (int pt = 0; pt < 4; ++pt) {
      f32x4 Cb = (f32x4)(0.f);
#pragma unroll
      for (int K = 0; K < 4; ++K) {
        bf16x8 Bb = *(const bf16x8*)&Ab[(pt * 16 + lm) * 128 + K * 32 + lq * 8];
        Cb = __builtin_amdgcn_mfma_f32_16x16x32_bf16(Abh[K], Bb, Cb, 0, 0, 0);
        Cb = __builtin_amdgcn_mfma_f32_16x16x32_bf16(Abl[K], Bb, Cb, 0, 0, 0);
      }
#pragma unroll
      for (int r = 0; r < 4; ++r)
        Tsw[pt * 16 + lm][lq * 4 + r] = Cb[r];
    }
    float4 bl4 = *(const float4*)&Tsw[x][gg * 4];
    const float blv[4] = {bl4.x, bl4.y, bl4.z, bl4.w};
    ushort vh[4], vl[4];
#pragma unroll
    for (int i = 0; i < 4; ++i) {
      int ch = gi * 4 + i;
      size_t oidx = ((size_t)b * 256 + ch) * P_ + p0 + x;
      float x2v = (s4[i] + blv[i]) * ga1[ch] + uf_ep[oidx];
      float pr = x1[oidx] * x2v * sca[b * 256 + ch] * lka[oidx];
      ushort h = f2bf(pr);
      vh[i] = h;
      vl[i] = f2bf(pr - bf2f(h));
    }
    size_t xa = ((size_t)b * P_ + p0 + x) * 256 + quad * 16 + gg * 4;
    uint2 hv, lv;
    hv.x = pack2(vh[0], vh[1]); hv.y = pack2(vh[2], vh[3]);
    lv.x = pack2(vl[0], vl[1]); lv.y = pack2(vl[2], vl[3]);
    *(uint2*)&pXh[xa] = hv;
    *(uint2*)&pXl[xa] = lv;
  } else {
#pragma unroll
    for (int i = 0; i < 4; ++i) {
      int ch = gi * 4 + i;
      outV[((size_t)b * 256 + ch) * P_ + p0 + x] = s4[i];
    }
  }
}

// ---------------- standalone split-bf16 GEMM (proj) ----------------
__global__ __launch_bounds__(256) void gemm_bf16s_kernel(
    const ushort* __restrict__ Wh, const ushort* __restrict__ Wl,
    const ushort* __restrict__ Xh, const ushort* __restrict__ Xl,
    const float* __restrict__ bias, float* __restrict__ out, int M, int K) {
  __shared__ __align__(16) char smem[36864];
  int p0 = blockIdx.x * 64, m0 = blockIdx.y * 64, b = blockIdx.z;
  gemm_body(Wh + (size_t)m0 * K, Wl + (size_t)m0 * K,
            Xh + ((size_t)b * P_ + p0) * K, Xl + ((size_t)b * P_ + p0) * K,
            bias, out, M, m0, p0, b, K, smem);
}

extern "C" void kernel_launch(void* const* d_in, const int* in_sizes, int n_in,
                              void* d_out, int out_size, void* d_ws, size_t ws_size,
                              hipStream_t stream) {
  const float* x      = (const float*)d_in[0];
  const float* dw1_w  = (const float*)d_in[1];
  const float* dw2_w  = (const float*)d_in[2];
  const float* proj_w = (const float*)d_in[3];
  const float* lka0_w = (const float*)d_in[4];
  const float* lkas_w = (const float*)d_in[5];
  const float* lka1_w = (const float*)d_in[6];
  const float* lka1_b = (const float*)d_in[7];
  const float* sca_w  = (const float*)d_in[8];
  const float* sca_b  = (const float*)d_in[9];
  const float* c1a_w  = (const float*)d_in[10];
  const float* c1b_w  = (const float*)d_in[11];
  const float* c2a_w  = (const float*)d_in[12];
  const float* c2a_b  = (const float*)d_in[13];
  const float* c2b_w  = (const float*)d_in[14];
  const float* c2b_b  = (const float*)d_in[15];
  const float* c211_w = (const float*)d_in[16];
  const float* c211_b = (const float*)d_in[17];
  const float* w_cb   = (const float*)d_in[18];
  const float* b_cb   = (const float*)d_in[19];
  const float* attg   = (const float*)d_in[20];
  const float* ga1    = (const float*)d_in[21];
  float* out = (float*)d_out;

  const size_t NCHW = 2u * 256u * P_;
  float* ws = (float*)d_ws;
  size_t off = 0;
  float* meanb = ws + off; off += 512;
  float* scab  = ws + off; off += 512;
  float* B1 = ws + off; off += NCHW;   // lka1-out (lka)
  float* B2 = ws + off; off += NCHW;   // x1
  float* B3 = ws + off; off += NCHW;   // c1a-out
  float* B4 = ws + off; off += NCHW;   // dw1-out (dead after K3 dw2)
  float* B5 = ws + off; off += NCHW;   // uf
  float* B6 = ws + off; off += NCHW;   // lkas-out -> xh (ikbaV out)
  float* sb   = ws + off; off += 2u * 16u * P_;   // gated
  float* att0 = ws + off; off += 2u * 128u * P_;  // c211 out (fp32)
  ushort* wT    = (ushort*)(ws + off); off += 393216;   // [6144][128] bf16
  ushort* W5h   = (ushort*)(ws + off); off += 147456;
  ushort* W5l   = (ushort*)(ws + off); off += 147456;
  ushort* bth   = (ushort*)(ws + off); off += 16384;    // b_cb^T hi [256][128]
  ushort* btl   = (ushort*)(ws + off); off += 16384;
  ushort* XTxh  = (ushort*)(ws + off); off += 1048576;  // x^T [2][P][256]
  ushort* XTxl  = (ushort*)(ws + off); off += 1048576;
  ushort* XT2h  = (ushort*)(ws + off); off += 1048576;  // lkas^T
  ushort* XT2l  = (ushort*)(ws + off); off += 1048576;
  ushort* XT3h  = (ushort*)(ws + off); off += 1048576;  // product^T
  ushort* XT3l  = (ushort*)(ws + off); off += 1048576;
  ushort* attTh = (ushort*)(ws + off); off += 524288;   // att^T [2][P][128]
  ushort* attTl = (ushort*)(ws + off); off += 524288;

  const ushort* Wlka1h = W5h + 65536,  *Wlka1l = W5l + 65536;
  const ushort* Wprojh = W5h + 196608, *Wprojl = W5l + 196608;

  dim3 blk(256);

  // K1: lka chain (x -> B6) + weight prep + mean + xsplit(x)
  prep_kernel<<<1524, blk, 0, stream>>>(w_cb, dw1_w, lka1_w, c1a_w, proj_w,
                                        c211_w, b_cb, wT, W5h, W5l, bth, btl,
                                        x, meanb, XTxh, XTxl,
                                        lka0_w, lkas_w, B6);
  // K2: dw1 (->B4) / c1a (->B3) / c211 (->att0) GEMMs + c2a gate + xsplit(B6)
  //     + sca
  main1_kernel<<<2050, blk, 0, stream>>>(XTxh, XTxl, W5h, W5l, c211_b,
                                         B4, B3, att0, x, c2a_w, c2a_b, sb,
                                         B6, XT2h, XT2l, meanb, sca_w, sca_b,
                                         scab);
  // K3: lka1 GEMM (XT2 -> B1) + c2b_t (-> attT) + dw2 (B4 -> B2)
  //     + c1b (B3 -> B5)
  k3_kernel<<<1792, blk, 0, stream>>>(Wlka1h, Wlka1l, XT2h, XT2l, lka1_b, B1,
                                      sb, c2b_w, c2b_b, attg, att0,
                                      attTh, attTl,
                                      B4, dw2_w, B2, B3, c1b_w, B5);
  // K4: IKBA vertical (uf=B5 -> xh=B6; B6 dead after K2's xsplit)
  dim3 gik(64, 16, 2);
  ikba_mfma_kernel<<<gik, blk, 0, stream>>>(B5, attTh, wT, 0, 0, nullptr, nullptr,
                                            nullptr, nullptr, nullptr, nullptr,
                                            nullptr, nullptr, nullptr, B6);
  // K5: IKBA horizontal + bias_t MFMA + product (x1=B2, lka=B1) -> XT3
  ikba_mfma_kernel<<<gik, blk, 0, stream>>>(B6, attTh, wT, 1, 3072, bth, btl,
                                            B5, ga1, B2, B1, scab, XT3h, XT3l,
                                            nullptr);
  // K6: proj GEMM -> out
  gemm_bf16s_kernel<<<dim3(64, 4, 2), blk, 0, stream>>>(Wprojh, Wprojl, XT3h,
                                                        XT3l, nullptr, out, 256, 256);
}

// Round 12
// 251.724 us; speedup vs baseline: 1.0898x; 1.0898x over previous
//
#include <hip/hip_runtime.h>
#include <cstddef>

#define P_ 4096   // H*W
#define HW_ 64

typedef __bf16 bf16x8 __attribute__((ext_vector_type(8)));
typedef float f32x4 __attribute__((ext_vector_type(4)));

__device__ inline ushort f2bf(float f) {
  unsigned u = __float_as_uint(f);
  unsigned r = (u + 0x7FFFu + ((u >> 16) & 1u)) >> 16;
  return (ushort)r;
}
__device__ inline float bf2f(ushort h) {
  return __uint_as_float(((unsigned)h) << 16);
}
__device__ inline unsigned pack2(ushort a, ushort b) {
  return (unsigned)a | ((unsigned)b << 16);
}

// ---------------- device helpers ----------------

// transpose+split one 128k x 64p tile: src [K][P] fp32 -> dst [P][K] bf16 hi/lo
__device__ inline void xsplit_body(const float* sb, ushort* dhb, ushort* dlb,
                                   int p0, int K, char* smem) {
  float (*T)[65] = (float(*)[65])smem;
  int t = threadIdx.x;
#pragma unroll
  for (int i = 0; i < 32; ++i) {
    int l = i * 256 + t;
    int n = l >> 6, c = l & 63;
    T[n][c] = sb[(size_t)n * P_ + p0 + c];
  }
  __syncthreads();
#pragma unroll
  for (int i = 0; i < 4; ++i) {
    int l = i * 256 + t;
    int c = l >> 4, n8 = (l & 15) << 3;
    ushort vh[8], vl[8];
#pragma unroll
    for (int u = 0; u < 8; ++u) {
      float f = T[n8 + u][c];
      ushort h = f2bf(f);
      vh[u] = h;
      vl[u] = f2bf(f - bf2f(h));
    }
    *(uint4*)&dhb[(size_t)(p0 + c) * K + n8] = *(uint4*)vh;
    *(uint4*)&dlb[(size_t)(p0 + c) * K + n8] = *(uint4*)vl;
  }
}

// split-bf16 GEMM 64x64 tile body (R7 proven version — NO register prefetch;
// R8's 64-VGPR prefetch spilled to scratch: WRITE_SIZE 29->110MB regression)
__device__ inline void gemm_body(const ushort* Whb, const ushort* Wlb,
                                 const ushort* Xhb, const ushort* Xlb,
                                 const float* bias, float* out, int M, int m0,
                                 int p0, int b, int K, char* smem) {
  ushort* Wsh = (ushort*)smem;
  ushort* Wsl = (ushort*)(smem + 9216);
  ushort* Xsh = (ushort*)(smem + 18432);
  ushort* Xsl = (ushort*)(smem + 27648);
  int t = threadIdx.x;
  int w = t >> 6, lane = t & 63, lm = lane & 15, lq = lane >> 4;
  f32x4 C[4];
#pragma unroll
  for (int pt = 0; pt < 4; ++pt) C[pt] = (f32x4)(0.f);
  for (int k0 = 0; k0 < K; k0 += 64) {
#pragma unroll
    for (int i = 0; i < 2; ++i) {
      int u = i * 256 + t;
      int row = u >> 3, k8 = (u & 7) * 8;
      *(uint4*)&Wsh[row * 72 + k8] = *(const uint4*)&Whb[(size_t)row * K + k0 + k8];
      *(uint4*)&Wsl[row * 72 + k8] = *(const uint4*)&Wlb[(size_t)row * K + k0 + k8];
      *(uint4*)&Xsh[row * 72 + k8] = *(const uint4*)&Xhb[(size_t)row * K + k0 + k8];
      *(uint4*)&Xsl[row * 72 + k8] = *(const uint4*)&Xlb[(size_t)row * K + k0 + k8];
    }
    __syncthreads();
#pragma unroll
    for (int kt = 0; kt < 2; ++kt) {
      bf16x8 Ah = *(const bf16x8*)&Wsh[(w * 16 + lm) * 72 + kt * 32 + lq * 8];
      bf16x8 Al = *(const bf16x8*)&Wsl[(w * 16 + lm) * 72 + kt * 32 + lq * 8];
#pragma unroll
      for (int pt = 0; pt < 4; ++pt) {
        bf16x8 Bh = *(const bf16x8*)&Xsh[(pt * 16 + lm) * 72 + kt * 32 + lq * 8];
        bf16x8 Bl = *(const bf16x8*)&Xsl[(pt * 16 + lm) * 72 + kt * 32 + lq * 8];
        C[pt] = __builtin_amdgcn_mfma_f32_16x16x32_bf16(Ah, Bh, C[pt], 0, 0, 0);
        C[pt] = __builtin_amdgcn_mfma_f32_16x16x32_bf16(Al, Bh, C[pt], 0, 0, 0);
        C[pt] = __builtin_amdgcn_mfma_f32_16x16x32_bf16(Ah, Bl, C[pt], 0, 0, 0);
      }
    }
    __syncthreads();
  }
#pragma unroll
  for (int pt = 0; pt < 4; ++pt) {
    int p = p0 + pt * 16 + lm;
#pragma unroll
    for (int r = 0; r < 4; ++r) {
      int m = m0 + w * 16 + lq * 4 + r;
      float v = C[pt][r];
      if (bias) v += bias[m];
      out[((size_t)b * M + m) * P_ + p] = v;
    }
  }
}

// ---------------- K1: lka chain + prep + mean + xsplit(x) ----------------
// grid 1524: [0,512) lka chain; [512,608) wT; [608,752) weight splits;
//            [752,756) b_cb^T; [756,1268) mean; [1268,1524) xsplit of x
__global__ __launch_bounds__(256) void prep_kernel(
    const float* __restrict__ w_cb, const float* __restrict__ dw1_w,
    const float* __restrict__ lka1_w, const float* __restrict__ c1a_w,
    const float* __restrict__ proj_w, const float* __restrict__ c211_w,
    const float* __restrict__ b_cb, ushort* __restrict__ wT,
    ushort* __restrict__ W5h, ushort* __restrict__ W5l,
    ushort* __restrict__ bth, ushort* __restrict__ btl,
    const float* __restrict__ x, float* __restrict__ mean,
    ushort* __restrict__ XTxh, ushort* __restrict__ XTxl,
    const float* __restrict__ w0, const float* __restrict__ w1,
    float* __restrict__ outlka) {
  __shared__ __align__(16) char smem[48448];
  float (*T)[65] = (float(*)[65])smem;
  int blk = blockIdx.x;
  int t = threadIdx.x;
  if (blk < 512) {
    // lka chain: 5x5 p2 -> 7x7 d3 p9, 4x4 register-blocked float4 LDS reads.
    float* p0a = (float*)smem;             // 68 x 72
    float* p1a = (float*)(smem + 19584);   // 82 x 88
    int bc = blk;
    const float* ib = x + (size_t)bc * P_;
    const float* wp0 = w0 + (size_t)(bc & 255) * 25;
    const float* wp1 = w1 + (size_t)(bc & 255) * 49;
    for (int i = t; i < 4896; i += 256) p0a[i] = 0.f;
    for (int i = t; i < 7216; i += 256) p1a[i] = 0.f;
    __syncthreads();
#pragma unroll
    for (int i = 0; i < 4; ++i) {
      int l = i * 1024 + t * 4;
      int y = l >> 6, xx = l & 63;
      *(float4*)&p0a[(y + 2) * 72 + 4 + xx] = *(const float4*)(ib + l);
    }
    __syncthreads();
    int x0 = (t & 15) * 4, y0 = (t >> 4) * 4;
    {
      float acc[4][4] = {};
#pragma unroll
      for (int ry = 0; ry < 8; ++ry) {
        const float* row = &p0a[(y0 + ry) * 72 + x0];
        float4 v0 = *(const float4*)row;
        float4 v1 = *(const float4*)(row + 4);
        float4 v2 = *(const float4*)(row + 8);
        float rv[12] = {v0.x, v0.y, v0.z, v0.w, v1.x, v1.y, v1.z, v1.w,
                        v2.x, v2.y, v2.z, v2.w};
#pragma unroll
        for (int oy = 0; oy < 4; ++oy) {
          int dy = ry - oy;
          if (dy >= 0 && dy <= 4) {
#pragma unroll
            for (int dx = 0; dx < 5; ++dx) {
              float wv = wp0[dy * 5 + dx];
#pragma unroll
              for (int ox = 0; ox < 4; ++ox)
                acc[oy][ox] += wv * rv[2 + ox + dx];
            }
          }
        }
      }
#pragma unroll
      for (int oy = 0; oy < 4; ++oy) {
        float4 v = {acc[oy][0], acc[oy][1], acc[oy][2], acc[oy][3]};
        *(float4*)&p1a[(y0 + oy + 9) * 88 + 12 + x0] = v;
      }
    }
    __syncthreads();
    {
      float acc[4][4] = {};
#pragma unroll
      for (int ry = 0; ry < 22; ++ry) {
        const float* row = &p1a[(y0 + ry) * 88 + x0];
        float rv[28];
#pragma unroll
        for (int q = 0; q < 7; ++q)
          *(float4*)&rv[q * 4] = *(const float4*)(row + q * 4);
#pragma unroll
        for (int oy = 0; oy < 4; ++oy) {
          int d = ry - oy;
          if (d >= 0 && d <= 18 && (d % 3) == 0) {
            int dy = d / 3;
#pragma unroll
            for (int dx = 0; dx < 7; ++dx) {
              float wv = wp1[dy * 7 + dx];
#pragma unroll
              for (int ox = 0; ox < 4; ++ox)
                acc[oy][ox] += wv * rv[3 + ox + 3 * dx];
            }
          }
        }
      }
      float* ob = outlka + (size_t)bc * P_;
#pragma unroll
      for (int oy = 0; oy < 4; ++oy) {
        float4 v = {acc[oy][0], acc[oy][1], acc[oy][2], acc[oy][3]};
        *(float4*)&ob[(y0 + oy) * 64 + x0] = v;
      }
    }
  } else if (blk < 608) {
    int c0 = (blk - 512) * 64;
#pragma unroll
    for (int i = 0; i < 32; ++i) {
      int l = i * 256 + t;
      int n = l >> 6, c = l & 63;
      T[n][c] = w_cb[(size_t)n * 6144 + c0 + c];
    }
    __syncthreads();
#pragma unroll
    for (int i = 0; i < 4; ++i) {
      int l = i * 256 + t;
      int c = l >> 4, n8 = (l & 15) << 3;
      ushort v[8];
#pragma unroll
      for (int u = 0; u < 8; ++u) v[u] = f2bf(T[n8 + u][c]);
      *(uint4*)&wT[(size_t)(c0 + c) * 128 + n8] = *(uint4*)v;
    }
  } else if (blk < 752) {
    int f = (blk - 608) * 2048 + t * 8;
    const float* srcs[5] = {dw1_w, lka1_w, c1a_w, proj_w, c211_w};
    const int base[6] = {0, 65536, 131072, 196608, 262144, 294912};
    int r = 0;
    while (f >= base[r + 1]) ++r;
    const float* s = srcs[r] + (f - base[r]);
    float4 a = *(const float4*)s;
    float4 b4 = *(const float4*)(s + 4);
    float vv[8] = {a.x, a.y, a.z, a.w, b4.x, b4.y, b4.z, b4.w};
    ushort vh[8], vl[8];
#pragma unroll
    for (int u = 0; u < 8; ++u) {
      ushort h = f2bf(vv[u]);
      vh[u] = h;
      vl[u] = f2bf(vv[u] - bf2f(h));
    }
    *(uint4*)&W5h[f] = *(uint4*)vh;
    *(uint4*)&W5l[f] = *(uint4*)vl;
  } else if (blk < 756) {
    int c0 = (blk - 752) * 64;
#pragma unroll
    for (int i = 0; i < 32; ++i) {
      int l = i * 256 + t;
      int n = l >> 6, c = l & 63;
      T[n][c] = b_cb[(size_t)n * 256 + c0 + c];
    }
    __syncthreads();
#pragma unroll
    for (int i = 0; i < 4; ++i) {
      int l = i * 256 + t;
      int c = l >> 4, n8 = (l & 15) << 3;
      ushort vh[8], vl[8];
#pragma unroll
      for (int u = 0; u < 8; ++u) {
        float fv = T[n8 + u][c];
        ushort h = f2bf(fv);
        vh[u] = h;
        vl[u] = f2bf(fv - bf2f(h));
      }
      *(uint4*)&bth[(size_t)(c0 + c) * 128 + n8] = *(uint4*)vh;
      *(uint4*)&btl[(size_t)(c0 + c) * 128 + n8] = *(uint4*)vl;
    }
  } else if (blk < 1268) {
    int bc = blk - 756;
    const float* xp = x + (size_t)bc * P_;
    float s = 0.f;
    for (int i = t; i < P_; i += 256) s += xp[i];
    float* red = (float*)smem;
    red[t] = s;
    __syncthreads();
    for (int off2 = 128; off2 > 0; off2 >>= 1) {
      if (t < off2) red[t] += red[t + off2];
      __syncthreads();
    }
    if (t == 0) mean[bc] = red[0] * (1.f / P_);
  } else {
    const int K = 256;
    int l = blk - 1268;
    int p0 = (l & 63) * 64;
    int kb = (l >> 6) & 1;
    int b = l >> 7;
    xsplit_body(x + ((size_t)b * K + kb * 128) * P_,
                XTxh + (size_t)b * P_ * K + (size_t)kb * 128,
                XTxl + (size_t)b * P_ * K + (size_t)kb * 128, p0, K, smem);
  }
}

// ---------------- K2: dw1/c1a/c211 GEMMs + c2a gate + xsplit(B6) + sca --------
// grid 2050: [0,1280) gemm tiles; [1280,1792) gate; [1792,2048) xsplit(B6);
//            [2048,2050) sca
__global__ __launch_bounds__(256) void main1_kernel(
    const ushort* __restrict__ Xh, const ushort* __restrict__ Xl,
    const ushort* __restrict__ W5h, const ushort* __restrict__ W5l,
    const float* __restrict__ c211_b, float* __restrict__ dw1_out,
    float* __restrict__ B3, float* __restrict__ att0,
    const float* __restrict__ x, const float* __restrict__ c2aw,
    const float* __restrict__ c2ab, float* __restrict__ sgate,
    const float* __restrict__ B6, ushort* __restrict__ XT2h,
    ushort* __restrict__ XT2l, const float* __restrict__ mean,
    const float* __restrict__ sca_w, const float* __restrict__ sca_b,
    float* __restrict__ sca) {
  __shared__ __align__(16) char smem[36864];
  int blk = blockIdx.x;
  int t = threadIdx.x;
  if (blk < 1280) {
    const int K = 256;
    int p = blk & 63;
    int my = (blk >> 6) % 10;
    int b = blk / 640;
    const ushort *Wh, *Wl;
    float* out;
    const float* bias = nullptr;
    int M, m0;
    if (my < 4) {
      Wh = W5h; Wl = W5l; out = dw1_out; M = 256; m0 = my * 64;
    } else if (my < 8) {
      Wh = W5h + 131072; Wl = W5l + 131072; out = B3; M = 256; m0 = (my - 4) * 64;
    } else {
      Wh = W5h + 262144; Wl = W5l + 262144; out = att0; M = 128;
      m0 = (my - 8) * 64; bias = c211_b;
    }
    int p0 = p * 64;
    gemm_body(Wh + (size_t)m0 * K, Wl + (size_t)m0 * K,
              Xh + ((size_t)b * P_ + p0) * K, Xl + ((size_t)b * P_ + p0) * K,
              bias, out, M, m0, p0, b, K, smem);
  } else if (blk < 1792) {
    int idx = (blk - 1280) * 256 + t;
    int xq = idx & 63, y = (idx >> 6) & 63, go = (idx >> 12) & 15, b = idx >> 16;
    float acc[2];
#pragma unroll
    for (int h = 0; h < 2; ++h) {
      int gc = go + h * 16;
      const float* wr = c2aw + gc * 72;
      const float* xb = x + ((size_t)b * 256 + gc * 8) * P_;
      float ss = c2ab[gc];
      for (int ci = 0; ci < 8; ++ci)
        for (int dy = 0; dy < 3; ++dy) {
          int yy = y + dy - 1;
          if (yy < 0 || yy >= 64) continue;
          for (int dx = 0; dx < 3; ++dx) {
            int xx = xq + dx - 1;
            if (xx < 0 || xx >= 64) continue;
            ss += wr[ci * 9 + dy * 3 + dx] * xb[(size_t)ci * P_ + yy * 64 + xx];
          }
        }
      acc[h] = ss;
    }
    sgate[idx] = acc[0] * acc[1];
  } else if (blk < 2048) {
    const int K = 256;
    int l = blk - 1792;
    int p0 = (l & 63) * 64;
    int kb = (l >> 6) & 1;
    int b = l >> 7;
    xsplit_body(B6 + ((size_t)b * K + kb * 128) * P_,
                XT2h + (size_t)b * P_ * K + (size_t)kb * 128,
                XT2l + (size_t)b * P_ * K + (size_t)kb * 128, p0, K, smem);
  } else {
    int b = blk - 2048, c = t;
    const float* mb = mean + b * 256;
    const float* wr = sca_w + c * 256;
    float s = sca_b[c];
    for (int k = 0; k < 256; ++k) s += wr[k] * mb[k];
    sca[b * 256 + c] = s;
  }
}

// ---------------- K3: lka1 GEMM + c2b_t + dw2/c1b 3x3 planes ----------------
// grid 1792: [0,512) lka1 gemm -> B1; [512,768) c2b_t; [768,1792) dw planes
__global__ __launch_bounds__(256) void k3_kernel(
    const ushort* __restrict__ Wh, const ushort* __restrict__ Wl,
    const ushort* __restrict__ XT2h, const ushort* __restrict__ XT2l,
    const float* __restrict__ lka1_b, float* __restrict__ B1,
    const float* __restrict__ sb, const float* __restrict__ c2bw,
    const float* __restrict__ c2bb, const float* __restrict__ gamma,
    const float* __restrict__ res, ushort* __restrict__ outh,
    ushort* __restrict__ outl, const float* __restrict__ in1,
    const float* __restrict__ w1, float* __restrict__ out1,
    const float* __restrict__ in2, const float* __restrict__ w2,
    float* __restrict__ out2) {
  __shared__ __align__(16) char smem[36864];
  int blk = blockIdx.x;
  int t = threadIdx.x;
  if (blk < 512) {
    const int K = 256;
    int p0 = (blk & 63) * 64;
    int m0 = ((blk >> 6) & 3) * 64;
    int b = blk >> 8;
    gemm_body(Wh + (size_t)m0 * K, Wl + (size_t)m0 * K,
              XT2h + ((size_t)b * P_ + p0) * K, XT2l + ((size_t)b * P_ + p0) * K,
              lka1_b, B1, 256, m0, p0, b, K, smem);
  } else if (blk < 768) {
    const int K = 16, M = 128;
    int l = blk - 512;
    int p0 = (l & 63) * 64;
    int m0 = ((l >> 6) & 1) * 64;
    int b = l >> 7;
    float (*Ws)[68] = (float(*)[68])smem;
    float (*Xs)[68] = (float(*)[68])(smem + 4352 * 4);
    int tm = t >> 4, tp = t & 15;
    float acc[4][4] = {};
    const float* inb = sb + (size_t)b * K * P_;
    {
      int kk = t >> 4, pq = (t & 15) << 2;
      float4 v = *(const float4*)(inb + (size_t)kk * P_ + p0 + pq);
      *(float4*)&Xs[kk][pq] = v;
    }
    {
      int mm = t >> 2, kq = (t & 3) << 2;
      float4 v = *(const float4*)(c2bw + (size_t)(m0 + mm) * K + kq);
      Ws[kq + 0][mm] = v.x; Ws[kq + 1][mm] = v.y;
      Ws[kq + 2][mm] = v.z; Ws[kq + 3][mm] = v.w;
    }
    __syncthreads();
#pragma unroll
    for (int kk = 0; kk < 16; ++kk) {
      const float4 wv = *(const float4*)&Ws[kk][tm << 2];
      const float4 xv = *(const float4*)&Xs[kk][tp << 2];
      const float wa[4] = {wv.x, wv.y, wv.z, wv.w};
      const float xa[4] = {xv.x, xv.y, xv.z, xv.w};
#pragma unroll
      for (int i = 0; i < 4; ++i)
#pragma unroll
        for (int j = 0; j < 4; ++j) acc[i][j] += wa[i] * xa[j];
    }
    float val[4][4];
#pragma unroll
    for (int i = 0; i < 4; ++i) {
      int m = m0 + (tm << 2) + i;
      float bv = c2bb[m], gm = gamma[m];
      float4 rv = *(const float4*)(res + ((size_t)b * M + m) * P_ + p0 + (tp << 2));
      val[i][0] = (acc[i][0] + bv) * gm + rv.x;
      val[i][1] = (acc[i][1] + bv) * gm + rv.y;
      val[i][2] = (acc[i][2] + bv) * gm + rv.z;
      val[i][3] = (acc[i][3] + bv) * gm + rv.w;
    }
#pragma unroll
    for (int j = 0; j < 4; ++j) {
      int p = p0 + (tp << 2) + j;
      ushort vh[4], vl[4];
#pragma unroll
      for (int i = 0; i < 4; ++i) {
        float f = val[i][j];
        ushort h = f2bf(f);
        vh[i] = h;
        vl[i] = f2bf(f - bf2f(h));
      }
      size_t a = ((size_t)b * P_ + p) * 128 + m0 + (tm << 2);
      uint2 hv, lv;
      hv.x = pack2(vh[0], vh[1]); hv.y = pack2(vh[2], vh[3]);
      lv.x = pack2(vl[0], vl[1]); lv.y = pack2(vl[2], vl[3]);
      *(uint2*)&outh[a] = hv;
      *(uint2*)&outl[a] = lv;
    }
  } else {
    // 3x3 depthwise plane: 66 rows x 72 cols, interior at [(y+1)*72 + 4 + x]
    float* pl = (float*)smem;
    int l = blk - 768;
    int which = l >> 9;
    int bc = l & 511;
    const float* in = which ? in2 : in1;
    const float* w = which ? w2 : w1;
    float* out = which ? out2 : out1;
    const float* ib = in + (size_t)bc * P_;
    const float* wp = w + (size_t)(bc & 255) * 9;
    for (int i = t; i < 4752; i += 256) pl[i] = 0.f;
    __syncthreads();
#pragma unroll
    for (int i = 0; i < 4; ++i) {
      int ll = i * 1024 + t * 4;
      int y = ll >> 6, xx = ll & 63;
      *(float4*)&pl[(y + 1) * 72 + 4 + xx] = *(const float4*)(ib + ll);
    }
    __syncthreads();
    int x0 = (t & 15) * 4, y0 = (t >> 4) * 4;
    float acc[4][4] = {};
#pragma unroll
    for (int ry = 0; ry < 6; ++ry) {
      const float* row = &pl[(y0 + ry) * 72 + x0];
      float4 v0 = *(const float4*)row;
      float4 v1 = *(const float4*)(row + 4);
      float4 v2 = *(const float4*)(row + 8);
      float rv[12] = {v0.x, v0.y, v0.z, v0.w, v1.x, v1.y, v1.z, v1.w,
                      v2.x, v2.y, v2.z, v2.w};
#pragma unroll
      for (int oy = 0; oy < 4; ++oy) {
        int dy = ry - oy;
        if (dy >= 0 && dy <= 2) {
#pragma unroll
          for (int dx = 0; dx < 3; ++dx) {
            float wv = wp[dy * 3 + dx];
#pragma unroll
            for (int ox = 0; ox < 4; ++ox)
              acc[oy][ox] += wv * rv[3 + ox + dx];
          }
        }
      }
    }
    float* ob = out + (size_t)bc * P_;
#pragma unroll
    for (int oy = 0; oy < 4; ++oy) {
      float4 v = {acc[oy][0], acc[oy][1], acc[oy][2], acc[oy][3]};
      *(float4*)&ob[(y0 + oy) * 64 + x0] = v;
    }
  }
}

// ---------------- K4: IKBA fused V+H, wave-private, barrier-free -------------
// grid (64 rows, 16 quads, B), block 256 = 4 independent waves.
// Wave gg owns group gi=quad*4+gg. V: attk-V MFMA -> transpose -> vertical
// taps from uf -> xh[4][64] kept in wave-private LDS (with x-halo). H: attk-H
// MFMA (+bias MFMA) -> transpose -> horizontal taps from the SAME wave's xh
// (H unfold is along x within the row; channels match the wave's group) ->
// epilogue product -> transposed bf16 hi/lo output. No __syncthreads, no xh
// HBM round trip, att row tile amortized across both passes.
__global__ __launch_bounds__(256) void ikba_fused_kernel(
    const float* __restrict__ uf, const ushort* __restrict__ attT,
    const ushort* __restrict__ Wt, const ushort* __restrict__ bth,
    const ushort* __restrict__ btl, const float* __restrict__ ga1,
    const float* __restrict__ x1, const float* __restrict__ lka,
    const float* __restrict__ sca, ushort* __restrict__ pXh,
    ushort* __restrict__ pXl) {
  __shared__ float Ts[4][64][17];  // transpose scratch, wave-private [gg]
  __shared__ float XH[4][4][68];   // xh + halo, wave-private [gg]

  int t = threadIdx.x;
  int b = blockIdx.z, quad = blockIdx.y, y = blockIdx.x;
  int p0 = y * 64;
  int gg = t >> 6, lane = t & 63;
  int lm = lane & 15, lq = lane >> 4;
  int gi = quad * 4 + gg;
  int x = lane;
  float (*Tsw)[17] = Ts[gg];
  float (*XHw)[68] = XH[gg];

  const ushort* Ab = attT + ((size_t)b * P_ + p0) * 128;
  const float* ufb = uf + ((size_t)b * 256 + gi * 4) * P_;
  float uf_mid[4];  // uf at row y (reused by epilogue)

  // ================= V phase =================
  {
    const ushort* Wbase = Wt + (size_t)gi * 48 * 128;  // V half (wofs 0)
    bf16x8 Af[3][4];
#pragma unroll
    for (int ct = 0; ct < 3; ++ct)
#pragma unroll
      for (int K = 0; K < 4; ++K)
        Af[ct][K] = *(const bf16x8*)&Wbase[(ct * 16 + lm) * 128 + K * 32 + lq * 8];
    f32x4 Cf[3][4];
#pragma unroll
    for (int ct = 0; ct < 3; ++ct)
#pragma unroll
      for (int pt = 0; pt < 4; ++pt) Cf[ct][pt] = (f32x4)(0.f);
#pragma unroll
    for (int pt = 0; pt < 4; ++pt) {
      bf16x8 Bf[4];
#pragma unroll
      for (int K = 0; K < 4; ++K)
        Bf[K] = *(const bf16x8*)&Ab[(pt * 16 + lm) * 128 + K * 32 + lq * 8];
#pragma unroll
      for (int ct = 0; ct < 3; ++ct)
#pragma unroll
        for (int K = 0; K < 4; ++K)
          Cf[ct][pt] = __builtin_amdgcn_mfma_f32_16x16x32_bf16(
              Af[ct][K], Bf[K], Cf[ct][pt], 0, 0, 0);
    }
    // vertical taps from uf (rows y-1, y, y+1)
    float u[12];
#pragma unroll
    for (int j = 0; j < 12; ++j) {
      int ci = j / 3, tap = j % 3;
      int yy = y + tap - 1;
      u[j] = (yy >= 0 && yy < 64) ? ufb[(size_t)ci * P_ + yy * 64 + x] : 0.f;
    }
#pragma unroll
    for (int ci = 0; ci < 4; ++ci) uf_mid[ci] = u[ci * 3 + 1];
    // transpose + apply -> xh (wave-private LDS, no barriers)
    float s4[4] = {0.f, 0.f, 0.f, 0.f};
#pragma unroll
    for (int ct = 0; ct < 3; ++ct) {
#pragma unroll
      for (int pt = 0; pt < 4; ++pt)
#pragma unroll
        for (int r = 0; r < 4; ++r)
          Tsw[pt * 16 + lm][lq * 4 + r] = Cf[ct][pt][r];
      float tv[16];
#pragma unroll
      for (int c4 = 0; c4 < 4; ++c4)
        *(float4*)&tv[c4 * 4] = *(const float4*)&Tsw[x][c4 * 4];
#pragma unroll
      for (int c = 0; c < 16; ++c) {
        int col = ct * 16 + c;
        int i = col / 12, j = col % 12;
        s4[i] += tv[c] * u[j];
      }
    }
    // stash xh with halo: index x+tap (tap-1 shifted by +1), halo [0],[65]=0
    if (lane < 2) {
#pragma unroll
      for (int ci = 0; ci < 4; ++ci) XHw[ci][lane * 65] = 0.f;
    }
#pragma unroll
    for (int ci = 0; ci < 4; ++ci) XHw[ci][x + 1] = s4[ci];
  }

  // ================= H phase =================
  {
    const ushort* Wbase = Wt + ((size_t)3072 + (size_t)gi * 48) * 128;  // H half
    bf16x8 Af[3][4];
#pragma unroll
    for (int ct = 0; ct < 3; ++ct)
#pragma unroll
      for (int K = 0; K < 4; ++K)
        Af[ct][K] = *(const bf16x8*)&Wbase[(ct * 16 + lm) * 128 + K * 32 + lq * 8];
    bf16x8 Abh[4], Abl[4];
#pragma unroll
    for (int K = 0; K < 4; ++K) {
      Abh[K] = *(const bf16x8*)&bth[(size_t)(quad * 16 + lm) * 128 + K * 32 + lq * 8];
      Abl[K] = *(const bf16x8*)&btl[(size_t)(quad * 16 + lm) * 128 + K * 32 + lq * 8];
    }
    f32x4 Ch[3][4];
#pragma unroll
    for (int ct = 0; ct < 3; ++ct)
#pragma unroll
      for (int pt = 0; pt < 4; ++pt) Ch[ct][pt] = (f32x4)(0.f);
    f32x4 Cb[4];
#pragma unroll
    for (int pt = 0; pt < 4; ++pt) Cb[pt] = (f32x4)(0.f);
#pragma unroll
    for (int pt = 0; pt < 4; ++pt) {
      bf16x8 Bf[4];
#pragma unroll
      for (int K = 0; K < 4; ++K)
        Bf[K] = *(const bf16x8*)&Ab[(pt * 16 + lm) * 128 + K * 32 + lq * 8];
#pragma unroll
      for (int ct = 0; ct < 3; ++ct)
#pragma unroll
        for (int K = 0; K < 4; ++K)
          Ch[ct][pt] = __builtin_amdgcn_mfma_f32_16x16x32_bf16(
              Af[ct][K], Bf[K], Ch[ct][pt], 0, 0, 0);
#pragma unroll
      for (int K = 0; K < 4; ++K) {
        Cb[pt] = __builtin_amdgcn_mfma_f32_16x16x32_bf16(Abh[K], Bf[K], Cb[pt], 0, 0, 0);
        Cb[pt] = __builtin_amdgcn_mfma_f32_16x16x32_bf16(Abl[K], Bf[K], Cb[pt], 0, 0, 0);
      }
    }
    // horizontal taps from the wave's own xh (LDS, halo at 0/65)
    float u[12];
#pragma unroll
    for (int j = 0; j < 12; ++j) {
      int ci = j / 3, tap = j % 3;
      u[j] = XHw[ci][x + tap];
    }
    float s4[4] = {0.f, 0.f, 0.f, 0.f};
#pragma unroll
    for (int ct = 0; ct < 3; ++ct) {
#pragma unroll
      for (int pt = 0; pt < 4; ++pt)
#pragma unroll
        for (int r = 0; r < 4; ++r)
          Tsw[pt * 16 + lm][lq * 4 + r] = Ch[ct][pt][r];
      float tv[16];
#pragma unroll
      for (int c4 = 0; c4 < 4; ++c4)
        *(float4*)&tv[c4 * 4] = *(const float4*)&Tsw[x][c4 * 4];
#pragma unroll
      for (int c = 0; c < 16; ++c) {
        int col = ct * 16 + c;
        int i = col / 12, j = col % 12;
        s4[i] += tv[c] * u[j];
      }
    }
    // bias tile transpose (16ch of quad x 64px), lane reads its group's 4
#pragma unroll
    for (int pt = 0; pt < 4; ++pt)
#pragma unroll
      for (int r = 0; r < 4; ++r)
        Tsw[pt * 16 + lm][lq * 4 + r] = Cb[pt][r];
    float4 bl4 = *(const float4*)&Tsw[x][gg * 4];
    const float blv[4] = {bl4.x, bl4.y, bl4.z, bl4.w};
    // epilogue: x2 = (xw + bias)*ga1 + uf ; pr = x1*x2*sca*lka
    ushort vh[4], vl[4];
#pragma unroll
    for (int i = 0; i < 4; ++i) {
      int ch = gi * 4 + i;
      size_t oidx = ((size_t)b * 256 + ch) * P_ + p0 + x;
      float x2v = (s4[i] + blv[i]) * ga1[ch] + uf_mid[i];
      float pr = x1[oidx] * x2v * sca[b * 256 + ch] * lka[oidx];
      ushort h = f2bf(pr);
      vh[i] = h;
      vl[i] = f2bf(pr - bf2f(h));
    }
    size_t xa = ((size_t)b * P_ + p0 + x) * 256 + quad * 16 + gg * 4;
    uint2 hv, lv;
    hv.x = pack2(vh[0], vh[1]); hv.y = pack2(vh[2], vh[3]);
    lv.x = pack2(vl[0], vl[1]); lv.y = pack2(vl[2], vl[3]);
    *(uint2*)&pXh[xa] = hv;
    *(uint2*)&pXl[xa] = lv;
  }
}

// ---------------- standalone split-bf16 GEMM (proj) ----------------
__global__ __launch_bounds__(256) void gemm_bf16s_kernel(
    const ushort* __restrict__ Wh, const ushort* __restrict__ Wl,
    const ushort* __restrict__ Xh, const ushort* __restrict__ Xl,
    const float* __restrict__ bias, float* __restrict__ out, int M, int K) {
  __shared__ __align__(16) char smem[36864];
  int p0 = blockIdx.x * 64, m0 = blockIdx.y * 64, b = blockIdx.z;
  gemm_body(Wh + (size_t)m0 * K, Wl + (size_t)m0 * K,
            Xh + ((size_t)b * P_ + p0) * K, Xl + ((size_t)b * P_ + p0) * K,
            bias, out, M, m0, p0, b, K, smem);
}

extern "C" void kernel_launch(void* const* d_in, const int* in_sizes, int n_in,
                              void* d_out, int out_size, void* d_ws, size_t ws_size,
                              hipStream_t stream) {
  const float* x      = (const float*)d_in[0];
  const float* dw1_w  = (const float*)d_in[1];
  const float* dw2_w  = (const float*)d_in[2];
  const float* proj_w = (const float*)d_in[3];
  const float* lka0_w = (const float*)d_in[4];
  const float* lkas_w = (const float*)d_in[5];
  const float* lka1_w = (const float*)d_in[6];
  const float* lka1_b = (const float*)d_in[7];
  const float* sca_w  = (const float*)d_in[8];
  const float* sca_b  = (const float*)d_in[9];
  const float* c1a_w  = (const float*)d_in[10];
  const float* c1b_w  = (const float*)d_in[11];
  const float* c2a_w  = (const float*)d_in[12];
  const float* c2a_b  = (const float*)d_in[13];
  const float* c2b_w  = (const float*)d_in[14];
  const float* c2b_b  = (const float*)d_in[15];
  const float* c211_w = (const float*)d_in[16];
  const float* c211_b = (const float*)d_in[17];
  const float* w_cb   = (const float*)d_in[18];
  const float* b_cb   = (const float*)d_in[19];
  const float* attg   = (const float*)d_in[20];
  const float* ga1    = (const float*)d_in[21];
  float* out = (float*)d_out;

  const size_t NCHW = 2u * 256u * P_;
  float* ws = (float*)d_ws;
  size_t off = 0;
  float* meanb = ws + off; off += 512;
  float* scab  = ws + off; off += 512;
  float* B1 = ws + off; off += NCHW;   // lka1-out (lka)
  float* B2 = ws + off; off += NCHW;   // x1
  float* B3 = ws + off; off += NCHW;   // c1a-out
  float* B4 = ws + off; off += NCHW;   // dw1-out (dead after K3 dw2)
  float* B5 = ws + off; off += NCHW;   // uf
  float* B6 = ws + off; off += NCHW;   // lkas-out
  float* sb   = ws + off; off += 2u * 16u * P_;   // gated
  float* att0 = ws + off; off += 2u * 128u * P_;  // c211 out (fp32)
  ushort* wT    = (ushort*)(ws + off); off += 393216;   // [6144][128] bf16
  ushort* W5h   = (ushort*)(ws + off); off += 147456;
  ushort* W5l   = (ushort*)(ws + off); off += 147456;
  ushort* bth   = (ushort*)(ws + off); off += 16384;    // b_cb^T hi [256][128]
  ushort* btl   = (ushort*)(ws + off); off += 16384;
  ushort* XTxh  = (ushort*)(ws + off); off += 1048576;  // x^T [2][P][256]
  ushort* XTxl  = (ushort*)(ws + off); off += 1048576;
  ushort* XT2h  = (ushort*)(ws + off); off += 1048576;  // lkas^T
  ushort* XT2l  = (ushort*)(ws + off); off += 1048576;
  ushort* XT3h  = (ushort*)(ws + off); off += 1048576;  // product^T
  ushort* XT3l  = (ushort*)(ws + off); off += 1048576;
  ushort* attTh = (ushort*)(ws + off); off += 524288;   // att^T [2][P][128]
  ushort* attTl = (ushort*)(ws + off); off += 524288;

  const ushort* Wlka1h = W5h + 65536,  *Wlka1l = W5l + 65536;
  const ushort* Wprojh = W5h + 196608, *Wprojl = W5l + 196608;

  dim3 blk(256);

  // K1: lka chain (x -> B6) + weight prep + mean + xsplit(x)
  prep_kernel<<<1524, blk, 0, stream>>>(w_cb, dw1_w, lka1_w, c1a_w, proj_w,
                                        c211_w, b_cb, wT, W5h, W5l, bth, btl,
                                        x, meanb, XTxh, XTxl,
                                        lka0_w, lkas_w, B6);
  // K2: dw1 (->B4) / c1a (->B3) / c211 (->att0) GEMMs + c2a gate + xsplit(B6)
  //     + sca
  main1_kernel<<<2050, blk, 0, stream>>>(XTxh, XTxl, W5h, W5l, c211_b,
                                         B4, B3, att0, x, c2a_w, c2a_b, sb,
                                         B6, XT2h, XT2l, meanb, sca_w, sca_b,
                                         scab);
  // K3: lka1 GEMM (XT2 -> B1) + c2b_t (-> attT) + dw2 (B4 -> B2)
  //     + c1b (B3 -> B5)
  k3_kernel<<<1792, blk, 0, stream>>>(Wlka1h, Wlka1l, XT2h, XT2l, lka1_b, B1,
                                      sb, c2b_w, c2b_b, attg, att0,
                                      attTh, attTl,
                                      B4, dw2_w, B2, B3, c1b_w, B5);
  // K4: fused IKBA V+H (uf=B5, x1=B2, lka=B1) -> XT3
  dim3 gik(64, 16, 2);
  ikba_fused_kernel<<<gik, blk, 0, stream>>>(B5, attTh, wT, bth, btl, ga1,
                                             B2, B1, scab, XT3h, XT3l);
  // K5: proj GEMM -> out
  gemm_bf16s_kernel<<<dim3(64, 4, 2), blk, 0, stream>>>(Wprojh, Wprojl, XT3h,
                                                        XT3l, nullptr, out, 256, 256);
}

// Round 14
// 226.155 us; speedup vs baseline: 1.2130x; 1.1131x over previous
//
#include <hip/hip_runtime.h>
#include <cstddef>

#define P_ 4096   // H*W
#define HW_ 64

typedef __bf16 bf16x8 __attribute__((ext_vector_type(8)));
typedef float f32x4 __attribute__((ext_vector_type(4)));

__device__ inline ushort f2bf(float f) {
  unsigned u = __float_as_uint(f);
  unsigned r = (u + 0x7FFFu + ((u >> 16) & 1u)) >> 16;
  return (ushort)r;
}
__device__ inline float bf2f(ushort h) {
  return __uint_as_float(((unsigned)h) << 16);
}
__device__ inline unsigned pack2(ushort a, ushort b) {
  return (unsigned)a | ((unsigned)b << 16);
}

// ---------------- device helpers ----------------

// transpose+split one 128k x 64p tile: src [K][P] fp32 -> dst [P][K] bf16 hi/lo
__device__ inline void xsplit_body(const float* sb, ushort* dhb, ushort* dlb,
                                   int p0, int K, char* smem) {
  float (*T)[65] = (float(*)[65])smem;
  int t = threadIdx.x;
#pragma unroll
  for (int i = 0; i < 32; ++i) {
    int l = i * 256 + t;
    int n = l >> 6, c = l & 63;
    T[n][c] = sb[(size_t)n * P_ + p0 + c];
  }
  __syncthreads();
#pragma unroll
  for (int i = 0; i < 4; ++i) {
    int l = i * 256 + t;
    int c = l >> 4, n8 = (l & 15) << 3;
    ushort vh[8], vl[8];
#pragma unroll
    for (int u = 0; u < 8; ++u) {
      float f = T[n8 + u][c];
      ushort h = f2bf(f);
      vh[u] = h;
      vl[u] = f2bf(f - bf2f(h));
    }
    *(uint4*)&dhb[(size_t)(p0 + c) * K + n8] = *(uint4*)vh;
    *(uint4*)&dlb[(size_t)(p0 + c) * K + n8] = *(uint4*)vl;
  }
}

// split-bf16 GEMM 64x64 tile body (R7 proven version — NO register prefetch;
// R8's 64-VGPR prefetch spilled to scratch: WRITE_SIZE 29->110MB regression)
__device__ inline void gemm_body(const ushort* Whb, const ushort* Wlb,
                                 const ushort* Xhb, const ushort* Xlb,
                                 const float* bias, float* out, int M, int m0,
                                 int p0, int b, int K, char* smem) {
  ushort* Wsh = (ushort*)smem;
  ushort* Wsl = (ushort*)(smem + 9216);
  ushort* Xsh = (ushort*)(smem + 18432);
  ushort* Xsl = (ushort*)(smem + 27648);
  int t = threadIdx.x;
  int w = t >> 6, lane = t & 63, lm = lane & 15, lq = lane >> 4;
  f32x4 C[4];
#pragma unroll
  for (int pt = 0; pt < 4; ++pt) C[pt] = (f32x4)(0.f);
  for (int k0 = 0; k0 < K; k0 += 64) {
#pragma unroll
    for (int i = 0; i < 2; ++i) {
      int u = i * 256 + t;
      int row = u >> 3, k8 = (u & 7) * 8;
      *(uint4*)&Wsh[row * 72 + k8] = *(const uint4*)&Whb[(size_t)row * K + k0 + k8];
      *(uint4*)&Wsl[row * 72 + k8] = *(const uint4*)&Wlb[(size_t)row * K + k0 + k8];
      *(uint4*)&Xsh[row * 72 + k8] = *(const uint4*)&Xhb[(size_t)row * K + k0 + k8];
      *(uint4*)&Xsl[row * 72 + k8] = *(const uint4*)&Xlb[(size_t)row * K + k0 + k8];
    }
    __syncthreads();
#pragma unroll
    for (int kt = 0; kt < 2; ++kt) {
      bf16x8 Ah = *(const bf16x8*)&Wsh[(w * 16 + lm) * 72 + kt * 32 + lq * 8];
      bf16x8 Al = *(const bf16x8*)&Wsl[(w * 16 + lm) * 72 + kt * 32 + lq * 8];
#pragma unroll
      for (int pt = 0; pt < 4; ++pt) {
        bf16x8 Bh = *(const bf16x8*)&Xsh[(pt * 16 + lm) * 72 + kt * 32 + lq * 8];
        bf16x8 Bl = *(const bf16x8*)&Xsl[(pt * 16 + lm) * 72 + kt * 32 + lq * 8];
        C[pt] = __builtin_amdgcn_mfma_f32_16x16x32_bf16(Ah, Bh, C[pt], 0, 0, 0);
        C[pt] = __builtin_amdgcn_mfma_f32_16x16x32_bf16(Al, Bh, C[pt], 0, 0, 0);
        C[pt] = __builtin_amdgcn_mfma_f32_16x16x32_bf16(Ah, Bl, C[pt], 0, 0, 0);
      }
    }
    __syncthreads();
  }
#pragma unroll
  for (int pt = 0; pt < 4; ++pt) {
    int p = p0 + pt * 16 + lm;
#pragma unroll
    for (int r = 0; r < 4; ++r) {
      int m = m0 + w * 16 + lq * 4 + r;
      float v = C[pt][r];
      if (bias) v += bias[m];
      out[((size_t)b * M + m) * P_ + p] = v;
    }
  }
}

// ---------------- K1: lka chain + prep + mean + xsplit(x) ----------------
// grid 1524: [0,512) lka chain; [512,608) wT; [608,752) weight splits;
//            [752,756) b_cb^T; [756,1268) mean; [1268,1524) xsplit of x
__global__ __launch_bounds__(256) void prep_kernel(
    const float* __restrict__ w_cb, const float* __restrict__ dw1_w,
    const float* __restrict__ lka1_w, const float* __restrict__ c1a_w,
    const float* __restrict__ proj_w, const float* __restrict__ c211_w,
    const float* __restrict__ b_cb, ushort* __restrict__ wT,
    ushort* __restrict__ W5h, ushort* __restrict__ W5l,
    ushort* __restrict__ bth, ushort* __restrict__ btl,
    const float* __restrict__ x, float* __restrict__ mean,
    ushort* __restrict__ XTxh, ushort* __restrict__ XTxl,
    const float* __restrict__ w0, const float* __restrict__ w1,
    float* __restrict__ outlka) {
  __shared__ __align__(16) char smem[48448];
  float (*T)[65] = (float(*)[65])smem;
  int blk = blockIdx.x;
  int t = threadIdx.x;
  if (blk < 512) {
    // lka chain: 5x5 p2 -> 7x7 d3 p9, 4x4 register-blocked float4 LDS reads.
    float* p0a = (float*)smem;             // 68 x 72
    float* p1a = (float*)(smem + 19584);   // 82 x 88
    int bc = blk;
    const float* ib = x + (size_t)bc * P_;
    const float* wp0 = w0 + (size_t)(bc & 255) * 25;
    const float* wp1 = w1 + (size_t)(bc & 255) * 49;
    for (int i = t; i < 4896; i += 256) p0a[i] = 0.f;
    for (int i = t; i < 7216; i += 256) p1a[i] = 0.f;
    __syncthreads();
#pragma unroll
    for (int i = 0; i < 4; ++i) {
      int l = i * 1024 + t * 4;
      int y = l >> 6, xx = l & 63;
      *(float4*)&p0a[(y + 2) * 72 + 4 + xx] = *(const float4*)(ib + l);
    }
    __syncthreads();
    int x0 = (t & 15) * 4, y0 = (t >> 4) * 4;
    {
      float acc[4][4] = {};
#pragma unroll
      for (int ry = 0; ry < 8; ++ry) {
        const float* row = &p0a[(y0 + ry) * 72 + x0];
        float4 v0 = *(const float4*)row;
        float4 v1 = *(const float4*)(row + 4);
        float4 v2 = *(const float4*)(row + 8);
        float rv[12] = {v0.x, v0.y, v0.z, v0.w, v1.x, v1.y, v1.z, v1.w,
                        v2.x, v2.y, v2.z, v2.w};
#pragma unroll
        for (int oy = 0; oy < 4; ++oy) {
          int dy = ry - oy;
          if (dy >= 0 && dy <= 4) {
#pragma unroll
            for (int dx = 0; dx < 5; ++dx) {
              float wv = wp0[dy * 5 + dx];
#pragma unroll
              for (int ox = 0; ox < 4; ++ox)
                acc[oy][ox] += wv * rv[2 + ox + dx];
            }
          }
        }
      }
#pragma unroll
      for (int oy = 0; oy < 4; ++oy) {
        float4 v = {acc[oy][0], acc[oy][1], acc[oy][2], acc[oy][3]};
        *(float4*)&p1a[(y0 + oy + 9) * 88 + 12 + x0] = v;
      }
    }
    __syncthreads();
    {
      float acc[4][4] = {};
#pragma unroll
      for (int ry = 0; ry < 22; ++ry) {
        const float* row = &p1a[(y0 + ry) * 88 + x0];
        float rv[28];
#pragma unroll
        for (int q = 0; q < 7; ++q)
          *(float4*)&rv[q * 4] = *(const float4*)(row + q * 4);
#pragma unroll
        for (int oy = 0; oy < 4; ++oy) {
          int d = ry - oy;
          if (d >= 0 && d <= 18 && (d % 3) == 0) {
            int dy = d / 3;
#pragma unroll
            for (int dx = 0; dx < 7; ++dx) {
              float wv = wp1[dy * 7 + dx];
#pragma unroll
              for (int ox = 0; ox < 4; ++ox)
                acc[oy][ox] += wv * rv[3 + ox + 3 * dx];
            }
          }
        }
      }
      float* ob = outlka + (size_t)bc * P_;
#pragma unroll
      for (int oy = 0; oy < 4; ++oy) {
        float4 v = {acc[oy][0], acc[oy][1], acc[oy][2], acc[oy][3]};
        *(float4*)&ob[(y0 + oy) * 64 + x0] = v;
      }
    }
  } else if (blk < 608) {
    int c0 = (blk - 512) * 64;
#pragma unroll
    for (int i = 0; i < 32; ++i) {
      int l = i * 256 + t;
      int n = l >> 6, c = l & 63;
      T[n][c] = w_cb[(size_t)n * 6144 + c0 + c];
    }
    __syncthreads();
#pragma unroll
    for (int i = 0; i < 4; ++i) {
      int l = i * 256 + t;
      int c = l >> 4, n8 = (l & 15) << 3;
      ushort v[8];
#pragma unroll
      for (int u = 0; u < 8; ++u) v[u] = f2bf(T[n8 + u][c]);
      *(uint4*)&wT[(size_t)(c0 + c) * 128 + n8] = *(uint4*)v;
    }
  } else if (blk < 752) {
    int f = (blk - 608) * 2048 + t * 8;
    const float* srcs[5] = {dw1_w, lka1_w, c1a_w, proj_w, c211_w};
    const int base[6] = {0, 65536, 131072, 196608, 262144, 294912};
    int r = 0;
    while (f >= base[r + 1]) ++r;
    const float* s = srcs[r] + (f - base[r]);
    float4 a = *(const float4*)s;
    float4 b4 = *(const float4*)(s + 4);
    float vv[8] = {a.x, a.y, a.z, a.w, b4.x, b4.y, b4.z, b4.w};
    ushort vh[8], vl[8];
#pragma unroll
    for (int u = 0; u < 8; ++u) {
      ushort h = f2bf(vv[u]);
      vh[u] = h;
      vl[u] = f2bf(vv[u] - bf2f(h));
    }
    *(uint4*)&W5h[f] = *(uint4*)vh;
    *(uint4*)&W5l[f] = *(uint4*)vl;
  } else if (blk < 756) {
    int c0 = (blk - 752) * 64;
#pragma unroll
    for (int i = 0; i < 32; ++i) {
      int l = i * 256 + t;
      int n = l >> 6, c = l & 63;
      T[n][c] = b_cb[(size_t)n * 256 + c0 + c];
    }
    __syncthreads();
#pragma unroll
    for (int i = 0; i < 4; ++i) {
      int l = i * 256 + t;
      int c = l >> 4, n8 = (l & 15) << 3;
      ushort vh[8], vl[8];
#pragma unroll
      for (int u = 0; u < 8; ++u) {
        float fv = T[n8 + u][c];
        ushort h = f2bf(fv);
        vh[u] = h;
        vl[u] = f2bf(fv - bf2f(h));
      }
      *(uint4*)&bth[(size_t)(c0 + c) * 128 + n8] = *(uint4*)vh;
      *(uint4*)&btl[(size_t)(c0 + c) * 128 + n8] = *(uint4*)vl;
    }
  } else if (blk < 1268) {
    int bc = blk - 756;
    const float* xp = x + (size_t)bc * P_;
    float s = 0.f;
    for (int i = t; i < P_; i += 256) s += xp[i];
    float* red = (float*)smem;
    red[t] = s;
    __syncthreads();
    for (int off2 = 128; off2 > 0; off2 >>= 1) {
      if (t < off2) red[t] += red[t + off2];
      __syncthreads();
    }
    if (t == 0) mean[bc] = red[0] * (1.f / P_);
  } else {
    const int K = 256;
    int l = blk - 1268;
    int p0 = (l & 63) * 64;
    int kb = (l >> 6) & 1;
    int b = l >> 7;
    xsplit_body(x + ((size_t)b * K + kb * 128) * P_,
                XTxh + (size_t)b * P_ * K + (size_t)kb * 128,
                XTxl + (size_t)b * P_ * K + (size_t)kb * 128, p0, K, smem);
  }
}

// ---------------- K2: dw1/c1a/c211 GEMMs + c2a gate + xsplit(B6) + sca --------
// grid 2050: [0,1280) gemm tiles; [1280,1792) gate; [1792,2048) xsplit(B6);
//            [2048,2050) sca
__global__ __launch_bounds__(256) void main1_kernel(
    const ushort* __restrict__ Xh, const ushort* __restrict__ Xl,
    const ushort* __restrict__ W5h, const ushort* __restrict__ W5l,
    const float* __restrict__ c211_b, float* __restrict__ dw1_out,
    float* __restrict__ B3, float* __restrict__ att0,
    const float* __restrict__ x, const float* __restrict__ c2aw,
    const float* __restrict__ c2ab, float* __restrict__ sgate,
    const float* __restrict__ B6, ushort* __restrict__ XT2h,
    ushort* __restrict__ XT2l, const float* __restrict__ mean,
    const float* __restrict__ sca_w, const float* __restrict__ sca_b,
    float* __restrict__ sca) {
  __shared__ __align__(16) char smem[36864];
  int blk = blockIdx.x;
  int t = threadIdx.x;
  if (blk < 1280) {
    const int K = 256;
    int p = blk & 63;
    int my = (blk >> 6) % 10;
    int b = blk / 640;
    const ushort *Wh, *Wl;
    float* out;
    const float* bias = nullptr;
    int M, m0;
    if (my < 4) {
      Wh = W5h; Wl = W5l; out = dw1_out; M = 256; m0 = my * 64;
    } else if (my < 8) {
      Wh = W5h + 131072; Wl = W5l + 131072; out = B3; M = 256; m0 = (my - 4) * 64;
    } else {
      Wh = W5h + 262144; Wl = W5l + 262144; out = att0; M = 128;
      m0 = (my - 8) * 64; bias = c211_b;
    }
    int p0 = p * 64;
    gemm_body(Wh + (size_t)m0 * K, Wl + (size_t)m0 * K,
              Xh + ((size_t)b * P_ + p0) * K, Xl + ((size_t)b * P_ + p0) * K,
              bias, out, M, m0, p0, b, K, smem);
  } else if (blk < 1792) {
    int idx = (blk - 1280) * 256 + t;
    int xq = idx & 63, y = (idx >> 6) & 63, go = (idx >> 12) & 15, b = idx >> 16;
    float acc[2];
#pragma unroll
    for (int h = 0; h < 2; ++h) {
      int gc = go + h * 16;
      const float* wr = c2aw + gc * 72;
      const float* xb = x + ((size_t)b * 256 + gc * 8) * P_;
      float ss = c2ab[gc];
      for (int ci = 0; ci < 8; ++ci)
        for (int dy = 0; dy < 3; ++dy) {
          int yy = y + dy - 1;
          if (yy < 0 || yy >= 64) continue;
          for (int dx = 0; dx < 3; ++dx) {
            int xx = xq + dx - 1;
            if (xx < 0 || xx >= 64) continue;
            ss += wr[ci * 9 + dy * 3 + dx] * xb[(size_t)ci * P_ + yy * 64 + xx];
          }
        }
      acc[h] = ss;
    }
    sgate[idx] = acc[0] * acc[1];
  } else if (blk < 2048) {
    const int K = 256;
    int l = blk - 1792;
    int p0 = (l & 63) * 64;
    int kb = (l >> 6) & 1;
    int b = l >> 7;
    xsplit_body(B6 + ((size_t)b * K + kb * 128) * P_,
                XT2h + (size_t)b * P_ * K + (size_t)kb * 128,
                XT2l + (size_t)b * P_ * K + (size_t)kb * 128, p0, K, smem);
  } else {
    int b = blk - 2048, c = t;
    const float* mb = mean + b * 256;
    const float* wr = sca_w + c * 256;
    float s = sca_b[c];
    for (int k = 0; k < 256; ++k) s += wr[k] * mb[k];
    sca[b * 256 + c] = s;
  }
}

// ---------------- K3: lka1 GEMM + c2b_t + dw2/c1b 3x3 planes ----------------
// grid 1792: [0,512) lka1 gemm -> B1; [512,768) c2b_t; [768,1792) dw planes
__global__ __launch_bounds__(256) void k3_kernel(
    const ushort* __restrict__ Wh, const ushort* __restrict__ Wl,
    const ushort* __restrict__ XT2h, const ushort* __restrict__ XT2l,
    const float* __restrict__ lka1_b, float* __restrict__ B1,
    const float* __restrict__ sb, const float* __restrict__ c2bw,
    const float* __restrict__ c2bb, const float* __restrict__ gamma,
    const float* __restrict__ res, ushort* __restrict__ outh,
    ushort* __restrict__ outl, const float* __restrict__ in1,
    const float* __restrict__ w1, float* __restrict__ out1,
    const float* __restrict__ in2, const float* __restrict__ w2,
    float* __restrict__ out2) {
  __shared__ __align__(16) char smem[36864];
  int blk = blockIdx.x;
  int t = threadIdx.x;
  if (blk < 512) {
    const int K = 256;
    int p0 = (blk & 63) * 64;
    int m0 = ((blk >> 6) & 3) * 64;
    int b = blk >> 8;
    gemm_body(Wh + (size_t)m0 * K, Wl + (size_t)m0 * K,
              XT2h + ((size_t)b * P_ + p0) * K, XT2l + ((size_t)b * P_ + p0) * K,
              lka1_b, B1, 256, m0, p0, b, K, smem);
  } else if (blk < 768) {
    const int K = 16, M = 128;
    int l = blk - 512;
    int p0 = (l & 63) * 64;
    int m0 = ((l >> 6) & 1) * 64;
    int b = l >> 7;
    float (*Ws)[68] = (float(*)[68])smem;
    float (*Xs)[68] = (float(*)[68])(smem + 4352 * 4);
    int tm = t >> 4, tp = t & 15;
    float acc[4][4] = {};
    const float* inb = sb + (size_t)b * K * P_;
    {
      int kk = t >> 4, pq = (t & 15) << 2;
      float4 v = *(const float4*)(inb + (size_t)kk * P_ + p0 + pq);
      *(float4*)&Xs[kk][pq] = v;
    }
    {
      int mm = t >> 2, kq = (t & 3) << 2;
      float4 v = *(const float4*)(c2bw + (size_t)(m0 + mm) * K + kq);
      Ws[kq + 0][mm] = v.x; Ws[kq + 1][mm] = v.y;
      Ws[kq + 2][mm] = v.z; Ws[kq + 3][mm] = v.w;
    }
    __syncthreads();
#pragma unroll
    for (int kk = 0; kk < 16; ++kk) {
      const float4 wv = *(const float4*)&Ws[kk][tm << 2];
      const float4 xv = *(const float4*)&Xs[kk][tp << 2];
      const float wa[4] = {wv.x, wv.y, wv.z, wv.w};
      const float xa[4] = {xv.x, xv.y, xv.z, xv.w};
#pragma unroll
      for (int i = 0; i < 4; ++i)
#pragma unroll
        for (int j = 0; j < 4; ++j) acc[i][j] += wa[i] * xa[j];
    }
    float val[4][4];
#pragma unroll
    for (int i = 0; i < 4; ++i) {
      int m = m0 + (tm << 2) + i;
      float bv = c2bb[m], gm = gamma[m];
      float4 rv = *(const float4*)(res + ((size_t)b * M + m) * P_ + p0 + (tp << 2));
      val[i][0] = (acc[i][0] + bv) * gm + rv.x;
      val[i][1] = (acc[i][1] + bv) * gm + rv.y;
      val[i][2] = (acc[i][2] + bv) * gm + rv.z;
      val[i][3] = (acc[i][3] + bv) * gm + rv.w;
    }
#pragma unroll
    for (int j = 0; j < 4; ++j) {
      int p = p0 + (tp << 2) + j;
      ushort vh[4], vl[4];
#pragma unroll
      for (int i = 0; i < 4; ++i) {
        float f = val[i][j];
        ushort h = f2bf(f);
        vh[i] = h;
        vl[i] = f2bf(f - bf2f(h));
      }
      size_t a = ((size_t)b * P_ + p) * 128 + m0 + (tm << 2);
      uint2 hv, lv;
      hv.x = pack2(vh[0], vh[1]); hv.y = pack2(vh[2], vh[3]);
      lv.x = pack2(vl[0], vl[1]); lv.y = pack2(vl[2], vl[3]);
      *(uint2*)&outh[a] = hv;
      *(uint2*)&outl[a] = lv;
    }
  } else {
    // 3x3 depthwise plane: 66 rows x 72 cols, interior at [(y+1)*72 + 4 + x]
    float* pl = (float*)smem;
    int l = blk - 768;
    int which = l >> 9;
    int bc = l & 511;
    const float* in = which ? in2 : in1;
    const float* w = which ? w2 : w1;
    float* out = which ? out2 : out1;
    const float* ib = in + (size_t)bc * P_;
    const float* wp = w + (size_t)(bc & 255) * 9;
    for (int i = t; i < 4752; i += 256) pl[i] = 0.f;
    __syncthreads();
#pragma unroll
    for (int i = 0; i < 4; ++i) {
      int ll = i * 1024 + t * 4;
      int y = ll >> 6, xx = ll & 63;
      *(float4*)&pl[(y + 1) * 72 + 4 + xx] = *(const float4*)(ib + ll);
    }
    __syncthreads();
    int x0 = (t & 15) * 4, y0 = (t >> 4) * 4;
    float acc[4][4] = {};
#pragma unroll
    for (int ry = 0; ry < 6; ++ry) {
      const float* row = &pl[(y0 + ry) * 72 + x0];
      float4 v0 = *(const float4*)row;
      float4 v1 = *(const float4*)(row + 4);
      float4 v2 = *(const float4*)(row + 8);
      float rv[12] = {v0.x, v0.y, v0.z, v0.w, v1.x, v1.y, v1.z, v1.w,
                      v2.x, v2.y, v2.z, v2.w};
#pragma unroll
      for (int oy = 0; oy < 4; ++oy) {
        int dy = ry - oy;
        if (dy >= 0 && dy <= 2) {
#pragma unroll
          for (int dx = 0; dx < 3; ++dx) {
            float wv = wp[dy * 3 + dx];
#pragma unroll
            for (int ox = 0; ox < 4; ++ox)
              acc[oy][ox] += wv * rv[3 + ox + dx];
          }
        }
      }
    }
    float* ob = out + (size_t)bc * P_;
#pragma unroll
    for (int oy = 0; oy < 4; ++oy) {
      float4 v = {acc[oy][0], acc[oy][1], acc[oy][2], acc[oy][3]};
      *(float4*)&ob[(y0 + oy) * 64 + x0] = v;
    }
  }
}

// ---------------- K4: IKBA fused V+H, att tile staged in LDS -----------------
// grid (64 rows, 16 quads, B), block 256 = 4 waves.
// v4 (fixed): the 64x128 att tile (= 1024 uint4, NOT 512 — R13's NaN was rows
// 32-63 never staged) is staged cooperatively ONCE per block. One
// __syncthreads after staging; everything downstream wave-private.
__global__ __launch_bounds__(256) void ikba_fused_kernel(
    const float* __restrict__ uf, const ushort* __restrict__ attT,
    const ushort* __restrict__ Wt, const ushort* __restrict__ bth,
    const ushort* __restrict__ btl, const float* __restrict__ ga1,
    const float* __restrict__ x1, const float* __restrict__ lka,
    const float* __restrict__ sca, ushort* __restrict__ pXh,
    ushort* __restrict__ pXl) {
  __shared__ ushort As[64 * 136];  // 17408 B staged att tile (pad 136)
  __shared__ float Ts[4][64][17];  // 17408 B transpose scratch, wave-private
  __shared__ float XH[4][4][68];   // 4352 B xh + halo, wave-private

  int t = threadIdx.x;
  int b = blockIdx.z, quad = blockIdx.y, y = blockIdx.x;
  int p0 = y * 64;
  int gg = t >> 6, lane = t & 63;
  int lm = lane & 15, lq = lane >> 4;
  int gi = quad * 4 + gg;
  int x = lane;
  float (*Tsw)[17] = Ts[gg];
  float (*XHw)[68] = XH[gg];

  // cooperative att tile stage: 64 rows x 128 n (bf16) = 1024 uint4
  const ushort* Ab = attT + ((size_t)b * P_ + p0) * 128;
#pragma unroll
  for (int i = 0; i < 4; ++i) {
    int l = i * 256 + t;
    int row = l >> 4, seg = l & 15;
    *(uint4*)&As[row * 136 + seg * 8] = *(const uint4*)&Ab[row * 128 + seg * 8];
  }
  __syncthreads();

  const float* ufb = uf + ((size_t)b * 256 + gi * 4) * P_;
  float uf_mid[4];  // uf at row y (reused by epilogue)

  // ================= V phase =================
  {
    const ushort* Wbase = Wt + (size_t)gi * 48 * 128;  // V half (wofs 0)
    bf16x8 Af[3][4];
#pragma unroll
    for (int ct = 0; ct < 3; ++ct)
#pragma unroll
      for (int K = 0; K < 4; ++K)
        Af[ct][K] = *(const bf16x8*)&Wbase[(ct * 16 + lm) * 128 + K * 32 + lq * 8];
    f32x4 Cf[3][4];
#pragma unroll
    for (int ct = 0; ct < 3; ++ct)
#pragma unroll
      for (int pt = 0; pt < 4; ++pt) Cf[ct][pt] = (f32x4)(0.f);
#pragma unroll
    for (int pt = 0; pt < 4; ++pt) {
      bf16x8 Bf[4];
#pragma unroll
      for (int K = 0; K < 4; ++K)
        Bf[K] = *(const bf16x8*)&As[(pt * 16 + lm) * 136 + K * 32 + lq * 8];
#pragma unroll
      for (int ct = 0; ct < 3; ++ct)
#pragma unroll
        for (int K = 0; K < 4; ++K)
          Cf[ct][pt] = __builtin_amdgcn_mfma_f32_16x16x32_bf16(
              Af[ct][K], Bf[K], Cf[ct][pt], 0, 0, 0);
    }
    // vertical taps from uf (rows y-1, y, y+1)
    float u[12];
#pragma unroll
    for (int j = 0; j < 12; ++j) {
      int ci = j / 3, tap = j % 3;
      int yy = y + tap - 1;
      u[j] = (yy >= 0 && yy < 64) ? ufb[(size_t)ci * P_ + yy * 64 + x] : 0.f;
    }
#pragma unroll
    for (int ci = 0; ci < 4; ++ci) uf_mid[ci] = u[ci * 3 + 1];
    // transpose + apply -> xh (wave-private LDS, no barriers)
    float s4[4] = {0.f, 0.f, 0.f, 0.f};
#pragma unroll
    for (int ct = 0; ct < 3; ++ct) {
#pragma unroll
      for (int pt = 0; pt < 4; ++pt)
#pragma unroll
        for (int r = 0; r < 4; ++r)
          Tsw[pt * 16 + lm][lq * 4 + r] = Cf[ct][pt][r];
      float tv[16];
#pragma unroll
      for (int c4 = 0; c4 < 4; ++c4)
        *(float4*)&tv[c4 * 4] = *(const float4*)&Tsw[x][c4 * 4];
#pragma unroll
      for (int c = 0; c < 16; ++c) {
        int col = ct * 16 + c;
        int i = col / 12, j = col % 12;
        s4[i] += tv[c] * u[j];
      }
    }
    // stash xh with halo: index x+tap (tap-1 shifted by +1), halo [0],[65]=0
    if (lane < 2) {
#pragma unroll
      for (int ci = 0; ci < 4; ++ci) XHw[ci][lane * 65] = 0.f;
    }
#pragma unroll
    for (int ci = 0; ci < 4; ++ci) XHw[ci][x + 1] = s4[ci];
  }

  // ================= H phase =================
  {
    const ushort* Wbase = Wt + ((size_t)3072 + (size_t)gi * 48) * 128;  // H half
    bf16x8 Af[3][4];
#pragma unroll
    for (int ct = 0; ct < 3; ++ct)
#pragma unroll
      for (int K = 0; K < 4; ++K)
        Af[ct][K] = *(const bf16x8*)&Wbase[(ct * 16 + lm) * 128 + K * 32 + lq * 8];
    bf16x8 Abh[4], Abl[4];
#pragma unroll
    for (int K = 0; K < 4; ++K) {
      Abh[K] = *(const bf16x8*)&bth[(size_t)(quad * 16 + lm) * 128 + K * 32 + lq * 8];
      Abl[K] = *(const bf16x8*)&btl[(size_t)(quad * 16 + lm) * 128 + K * 32 + lq * 8];
    }
    f32x4 Ch[3][4];
#pragma unroll
    for (int ct = 0; ct < 3; ++ct)
#pragma unroll
      for (int pt = 0; pt < 4; ++pt) Ch[ct][pt] = (f32x4)(0.f);
    f32x4 Cb[4];
#pragma unroll
    for (int pt = 0; pt < 4; ++pt) Cb[pt] = (f32x4)(0.f);
#pragma unroll
    for (int pt = 0; pt < 4; ++pt) {
      bf16x8 Bf[4];
#pragma unroll
      for (int K = 0; K < 4; ++K)
        Bf[K] = *(const bf16x8*)&As[(pt * 16 + lm) * 136 + K * 32 + lq * 8];
#pragma unroll
      for (int ct = 0; ct < 3; ++ct)
#pragma unroll
        for (int K = 0; K < 4; ++K)
          Ch[ct][pt] = __builtin_amdgcn_mfma_f32_16x16x32_bf16(
              Af[ct][K], Bf[K], Ch[ct][pt], 0, 0, 0);
#pragma unroll
      for (int K = 0; K < 4; ++K) {
        Cb[pt] = __builtin_amdgcn_mfma_f32_16x16x32_bf16(Abh[K], Bf[K], Cb[pt], 0, 0, 0);
        Cb[pt] = __builtin_amdgcn_mfma_f32_16x16x32_bf16(Abl[K], Bf[K], Cb[pt], 0, 0, 0);
      }
    }
    // horizontal taps from the wave's own xh (LDS, halo at 0/65)
    float u[12];
#pragma unroll
    for (int j = 0; j < 12; ++j) {
      int ci = j / 3, tap = j % 3;
      u[j] = XHw[ci][x + tap];
    }
    float s4[4] = {0.f, 0.f, 0.f, 0.f};
#pragma unroll
    for (int ct = 0; ct < 3; ++ct) {
#pragma unroll
      for (int pt = 0; pt < 4; ++pt)
#pragma unroll
        for (int r = 0; r < 4; ++r)
          Tsw[pt * 16 + lm][lq * 4 + r] = Ch[ct][pt][r];
      float tv[16];
#pragma unroll
      for (int c4 = 0; c4 < 4; ++c4)
        *(float4*)&tv[c4 * 4] = *(const float4*)&Tsw[x][c4 * 4];
#pragma unroll
      for (int c = 0; c < 16; ++c) {
        int col = ct * 16 + c;
        int i = col / 12, j = col % 12;
        s4[i] += tv[c] * u[j];
      }
    }
    // bias tile transpose (16ch of quad x 64px), lane reads its group's 4
#pragma unroll
    for (int pt = 0; pt < 4; ++pt)
#pragma unroll
      for (int r = 0; r < 4; ++r)
        Tsw[pt * 16 + lm][lq * 4 + r] = Cb[pt][r];
    float4 bl4 = *(const float4*)&Tsw[x][gg * 4];
    const float blv[4] = {bl4.x, bl4.y, bl4.z, bl4.w};
    // epilogue: x2 = (xw + bias)*ga1 + uf ; pr = x1*x2*sca*lka
    ushort vh[4], vl[4];
#pragma unroll
    for (int i = 0; i < 4; ++i) {
      int ch = gi * 4 + i;
      size_t oidx = ((size_t)b * 256 + ch) * P_ + p0 + x;
      float x2v = (s4[i] + blv[i]) * ga1[ch] + uf_mid[i];
      float pr = x1[oidx] * x2v * sca[b * 256 + ch] * lka[oidx];
      ushort h = f2bf(pr);
      vh[i] = h;
      vl[i] = f2bf(pr - bf2f(h));
    }
    size_t xa = ((size_t)b * P_ + p0 + x) * 256 + quad * 16 + gg * 4;
    uint2 hv, lv;
    hv.x = pack2(vh[0], vh[1]); hv.y = pack2(vh[2], vh[3]);
    lv.x = pack2(vl[0], vl[1]); lv.y = pack2(vl[2], vl[3]);
    *(uint2*)&pXh[xa] = hv;
    *(uint2*)&pXl[xa] = lv;
  }
}

// ---------------- standalone split-bf16 GEMM (proj) ----------------
__global__ __launch_bounds__(256) void gemm_bf16s_kernel(
    const ushort* __restrict__ Wh, const ushort* __restrict__ Wl,
    const ushort* __restrict__ Xh, const ushort* __restrict__ Xl,
    const float* __restrict__ bias, float* __restrict__ out, int M, int K) {
  __shared__ __align__(16) char smem[36864];
  int p0 = blockIdx.x * 64, m0 = blockIdx.y * 64, b = blockIdx.z;
  gemm_body(Wh + (size_t)m0 * K, Wl + (size_t)m0 * K,
            Xh + ((size_t)b * P_ + p0) * K, Xl + ((size_t)b * P_ + p0) * K,
            bias, out, M, m0, p0, b, K, smem);
}

extern "C" void kernel_launch(void* const* d_in, const int* in_sizes, int n_in,
                              void* d_out, int out_size, void* d_ws, size_t ws_size,
                              hipStream_t stream) {
  const float* x      = (const float*)d_in[0];
  const float* dw1_w  = (const float*)d_in[1];
  const float* dw2_w  = (const float*)d_in[2];
  const float* proj_w = (const float*)d_in[3];
  const float* lka0_w = (const float*)d_in[4];
  const float* lkas_w = (const float*)d_in[5];
  const float* lka1_w = (const float*)d_in[6];
  const float* lka1_b = (const float*)d_in[7];
  const float* sca_w  = (const float*)d_in[8];
  const float* sca_b  = (const float*)d_in[9];
  const float* c1a_w  = (const float*)d_in[10];
  const float* c1b_w  = (const float*)d_in[11];
  const float* c2a_w  = (const float*)d_in[12];
  const float* c2a_b  = (const float*)d_in[13];
  const float* c2b_w  = (const float*)d_in[14];
  const float* c2b_b  = (const float*)d_in[15];
  const float* c211_w = (const float*)d_in[16];
  const float* c211_b = (const float*)d_in[17];
  const float* w_cb   = (const float*)d_in[18];
  const float* b_cb   = (const float*)d_in[19];
  const float* attg   = (const float*)d_in[20];
  const float* ga1    = (const float*)d_in[21];
  float* out = (float*)d_out;

  const size_t NCHW = 2u * 256u * P_;
  float* ws = (float*)d_ws;
  size_t off = 0;
  float* meanb = ws + off; off += 512;
  float* scab  = ws + off; off += 512;
  float* B1 = ws + off; off += NCHW;   // lka1-out (lka)
  float* B2 = ws + off; off += NCHW;   // x1
  float* B3 = ws + off; off += NCHW;   // c1a-out
  float* B4 = ws + off; off += NCHW;   // dw1-out (dead after K3 dw2)
  float* B5 = ws + off; off += NCHW;   // uf
  float* B6 = ws + off; off += NCHW;   // lkas-out
  float* sb   = ws + off; off += 2u * 16u * P_;   // gated
  float* att0 = ws + off; off += 2u * 128u * P_;  // c211 out (fp32)
  ushort* wT    = (ushort*)(ws + off); off += 393216;   // [6144][128] bf16
  ushort* W5h   = (ushort*)(ws + off); off += 147456;
  ushort* W5l   = (ushort*)(ws + off); off += 147456;
  ushort* bth   = (ushort*)(ws + off); off += 16384;    // b_cb^T hi [256][128]
  ushort* btl   = (ushort*)(ws + off); off += 16384;
  ushort* XTxh  = (ushort*)(ws + off); off += 1048576;  // x^T [2][P][256]
  ushort* XTxl  = (ushort*)(ws + off); off += 1048576;
  ushort* XT2h  = (ushort*)(ws + off); off += 1048576;  // lkas^T
  ushort* XT2l  = (ushort*)(ws + off); off += 1048576;
  ushort* XT3h  = (ushort*)(ws + off); off += 1048576;  // product^T
  ushort* XT3l  = (ushort*)(ws + off); off += 1048576;
  ushort* attTh = (ushort*)(ws + off); off += 524288;   // att^T [2][P][128]
  ushort* attTl = (ushort*)(ws + off); off += 524288;

  const ushort* Wlka1h = W5h + 65536,  *Wlka1l = W5l + 65536;
  const ushort* Wprojh = W5h + 196608, *Wprojl = W5l + 196608;

  dim3 blk(256);

  // K1: lka chain (x -> B6) + weight prep + mean + xsplit(x)
  prep_kernel<<<1524, blk, 0, stream>>>(w_cb, dw1_w, lka1_w, c1a_w, proj_w,
                                        c211_w, b_cb, wT, W5h, W5l, bth, btl,
                                        x, meanb, XTxh, XTxl,
                                        lka0_w, lkas_w, B6);
  // K2: dw1 (->B4) / c1a (->B3) / c211 (->att0) GEMMs + c2a gate + xsplit(B6)
  //     + sca
  main1_kernel<<<2050, blk, 0, stream>>>(XTxh, XTxl, W5h, W5l, c211_b,
                                         B4, B3, att0, x, c2a_w, c2a_b, sb,
                                         B6, XT2h, XT2l, meanb, sca_w, sca_b,
                                         scab);
  // K3: lka1 GEMM (XT2 -> B1) + c2b_t (-> attT) + dw2 (B4 -> B2)
  //     + c1b (B3 -> B5)
  k3_kernel<<<1792, blk, 0, stream>>>(Wlka1h, Wlka1l, XT2h, XT2l, lka1_b, B1,
                                      sb, c2b_w, c2b_b, attg, att0,
                                      attTh, attTl,
                                      B4, dw2_w, B2, B3, c1b_w, B5);
  // K4: fused IKBA V+H (uf=B5, x1=B2, lka=B1) -> XT3
  dim3 gik(64, 16, 2);
  ikba_fused_kernel<<<gik, blk, 0, stream>>>(B5, attTh, wT, bth, btl, ga1,
                                             B2, B1, scab, XT3h, XT3l);
  // K5: proj GEMM -> out
  gemm_bf16s_kernel<<<dim3(64, 4, 2), blk, 0, stream>>>(Wprojh, Wprojl, XT3h,
                                                        XT3l, nullptr, out, 256, 256);
}